// Round 7
// baseline (568.889 us; speedup 1.0000x reference)
//
#include <hip/hip_runtime.h>
#include <cstdint>

typedef unsigned short u16;
typedef __attribute__((ext_vector_type(8))) __bf16 bf16x8;
typedef __attribute__((ext_vector_type(4))) float f32x4;

__device__ __forceinline__ u16 f2bf(float f) {
  unsigned int u = __builtin_bit_cast(unsigned int, f);
  unsigned int r = (u + 0x7fffu + ((u >> 16) & 1u)) >> 16;
  return (u16)r;
}

// async global->LDS, 16B per lane. LDS dest must be linear in lane (wave base + lane*16).
__device__ __forceinline__ void gload16(const u16* g, u16* l) {
  __builtin_amdgcn_global_load_lds((const __attribute__((address_space(1))) void*)g,
                                   (__attribute__((address_space(3))) void*)l, 16, 0, 0);
}

// XOR-swizzle helpers for flash kernel LDS.
__device__ __forceinline__ int swz64i(int row, int col) {   // 64 u16 cols per row
  return row * 64 + (((col & 0x38) ^ ((row & 7) << 3)) | (col & 7));
}
__device__ __forceinline__ int swz128i(int row, int col) {  // 128 u16 cols per row
  return row * 128 + (((col & 0x78) ^ ((row & 7) << 3)) | (col & 7));
}

// ---------------- fp32 -> bf16 conversion ----------------
__global__ __launch_bounds__(256) void cvt_bf16_kernel(const float* __restrict__ in,
                                                       u16* __restrict__ out, long n4) {
  long i = (long)blockIdx.x * 256 + threadIdx.x;
  long stride = (long)gridDim.x * 256;
  const float4* in4 = (const float4*)in;
  uint2* out2 = (uint2*)out;
  for (long k = i; k < n4; k += stride) {
    float4 v = in4[k];
    uint2 o;
    o.x = (unsigned int)f2bf(v.x) | ((unsigned int)f2bf(v.y) << 16);
    o.y = (unsigned int)f2bf(v.z) | ((unsigned int)f2bf(v.w) << 16);
    out2[k] = o;
  }
}

// ---------------- 256x256 8-phase bf16 GEMM (m201 geometry: wave = 128x64) --------------
// C[M][N] = A[M][K] * B[N][K]^T, fp32 C. BK=64, 512 thr, 8 waves 2Mx4N, acc[8][4].
// LDS 128KiB: A dbuf 2x32KB at 0, B dbuf 2x32KB at 32768(u16). Iter = 2 K-tiles, 8 phases.
// Stage 1 half-tile (2 gload_lds) per phase: t1's {A1,B0,B1} at ph1-3 (A0 at prev ph8),
// (t0+2)'s 4 halves at ph4-7, (t1+2)'s A0 at ph8. Drains: vmcnt(2) at ph4/ph8 end
// (vmcnt(0) in tail). Swizzle: 16B chunk ^ (row&7), pre-swizzled global source.
// Requires grid total % 8 == 0, K % 128 == 0.
__global__ __launch_bounds__(512, 2) void gemm256sq(const u16* __restrict__ A,
                                                    const u16* __restrict__ B,
                                                    float* __restrict__ C,
                                                    int Ndim, int Kdim) {
  extern __shared__ __align__(16) u16 lds[];
  const int tid = threadIdx.x;
  const int lane = tid & 63, wave = tid >> 6;
  const int wr = wave >> 2, wc = wave & 3;
  const int l15 = lane & 15, l4 = lane >> 4;
  const int gx = gridDim.x;
  int lin = blockIdx.y * gx + blockIdx.x;
  const int xcd = lin & 7, ii = lin >> 3;
  const int bx = xcd * (gx >> 3) + (ii >> 3), by = ii & 7;
  const long arow = (long)by * 256, brow = (long)bx * 256;
  const int NT = Kdim >> 6, NI = NT >> 1;

  const int rowt = tid >> 3;
  const int koff = ((tid & 7) ^ (rowt & 7)) * 8;
  const u16* gA[2][2];
  const u16* gB[2][2];
  #pragma unroll
  for (int h = 0; h < 2; ++h)
    #pragma unroll
    for (int g = 0; g < 2; ++g) {
      gA[h][g] = A + (size_t)(arow + h * 128 + g * 64 + rowt) * Kdim + koff;
      gB[h][g] = B + (size_t)(brow + h * 128 + g * 64 + rowt) * Kdim + koff;
    }

  auto STA = [&](int u, int h, int b) {   // A half h of tile u -> A-buf b
    u16* d = lds + b * 16384 + h * 8192 + tid * 8;
    gload16(gA[h][0] + (size_t)u * 64, d);
    gload16(gA[h][1] + (size_t)u * 64, d + 4096);
  };
  auto STB = [&](int u, int h, int b) {
    u16* d = lds + 32768 + b * 16384 + h * 8192 + tid * 8;
    gload16(gB[h][0] + (size_t)u * 64, d);
    gload16(gB[h][1] + (size_t)u * 64, d + 4096);
  };

  bf16x8 af[4][2], bfr0[2][2], bfr1[2][2];
  f32x4 acc[8][4] = {};
  int cks[2];
  #pragma unroll
  for (int kc = 0; kc < 2; ++kc) cks[kc] = (((kc * 4 + l4) ^ (l15 & 7)) * 8);

  auto LDA = [&](int b, int mh) {   // 8 x ds_read_b128
    const u16* base = lds + b * 16384 + (wr * 128 + mh * 64 + l15) * 64;
    #pragma unroll
    for (int m = 0; m < 4; ++m)
      #pragma unroll
      for (int kc = 0; kc < 2; ++kc)
        af[m][kc] = *(const bf16x8*)(base + m * 1024 + cks[kc]);
  };
  auto LDB = [&](int b, int nh, bf16x8 (*bf)[2]) {   // 4 x ds_read_b128
    const u16* base = lds + 32768 + b * 16384 + (wc * 64 + nh * 32 + l15) * 64;
    #pragma unroll
    for (int n = 0; n < 2; ++n)
      #pragma unroll
      for (int kc = 0; kc < 2; ++kc)
        bf[n][kc] = *(const bf16x8*)(base + n * 1024 + cks[kc]);
  };
  auto MMQ = [&](int mh, int nh, bf16x8 (*bf)[2]) {  // 16 MFMA, kc outermost
    #pragma unroll
    for (int kc = 0; kc < 2; ++kc)
      #pragma unroll
      for (int m = 0; m < 4; ++m)
        #pragma unroll
        for (int n = 0; n < 2; ++n)
          acc[mh * 4 + m][nh * 2 + n] =
            __builtin_amdgcn_mfma_f32_16x16x32_bf16(af[m][kc], bf[n][kc],
                                                    acc[mh * 4 + m][nh * 2 + n], 0, 0, 0);
  };

#define PH_BEGIN() do { __builtin_amdgcn_s_barrier();                         \
    asm volatile("s_waitcnt lgkmcnt(0)" ::: "memory");                        \
    __builtin_amdgcn_sched_barrier(0);                                        \
    __builtin_amdgcn_s_setprio(1); } while (0)
#define PH_END() do { __builtin_amdgcn_s_setprio(0);                          \
    __builtin_amdgcn_s_barrier(); } while (0)

  // prologue: tile0 all 4 halves -> buf0 (8 loads), tile1 A-half0 -> buf1 (2 loads)
  STA(0, 0, 0); STA(0, 1, 0); STB(0, 0, 0); STB(0, 1, 0);
  STA(1, 0, 1);
  asm volatile("s_waitcnt vmcnt(2)" ::: "memory");
  __builtin_amdgcn_s_barrier();

  for (int i = 0; i < NI; ++i) {
    const int t0 = 2 * i, t1 = 2 * i + 1;
    // ph1: Q(0,0) of t0
    LDA(0, 0); LDB(0, 0, bfr0);
    STA(t1, 1, 1);
    PH_BEGIN(); MMQ(0, 0, bfr0); PH_END();
    // ph2: Q(0,1)
    LDB(0, 1, bfr1);
    STB(t1, 0, 1);
    PH_BEGIN(); MMQ(0, 1, bfr1); PH_END();
    // ph3: Q(1,1)
    LDA(0, 1);
    STB(t1, 1, 1);
    PH_BEGIN(); MMQ(1, 1, bfr1); PH_END();
    // ph4: Q(1,0); stage (t0+2).A0; drain so buf1 (t1) is fully resident
    if (t0 + 2 < NT) STA(t0 + 2, 0, 0);
    PH_BEGIN(); MMQ(1, 0, bfr0);
    __builtin_amdgcn_s_setprio(0);
    if (t0 + 2 < NT) { asm volatile("s_waitcnt vmcnt(2)" ::: "memory"); }
    else             { asm volatile("s_waitcnt vmcnt(0)" ::: "memory"); }
    __builtin_amdgcn_s_barrier();
    // ph5: Q(0,0) of t1
    LDA(1, 0); LDB(1, 0, bfr0);
    if (t0 + 2 < NT) STA(t0 + 2, 1, 0);
    PH_BEGIN(); MMQ(0, 0, bfr0); PH_END();
    // ph6: Q(0,1)
    LDB(1, 1, bfr1);
    if (t0 + 2 < NT) STB(t0 + 2, 0, 0);
    PH_BEGIN(); MMQ(0, 1, bfr1); PH_END();
    // ph7: Q(1,1)
    LDA(1, 1);
    if (t0 + 2 < NT) STB(t0 + 2, 1, 0);
    PH_BEGIN(); MMQ(1, 1, bfr1); PH_END();
    // ph8: Q(1,0); stage (t1+2).A0; drain so buf0 (t0+2) is fully resident
    if (t1 + 2 < NT) STA(t1 + 2, 0, 1);
    PH_BEGIN(); MMQ(1, 0, bfr0);
    __builtin_amdgcn_s_setprio(0);
    if (t1 + 2 < NT) { asm volatile("s_waitcnt vmcnt(2)" ::: "memory"); }
    else             { asm volatile("s_waitcnt vmcnt(0)" ::: "memory"); }
    __builtin_amdgcn_s_barrier();
  }
#undef PH_BEGIN
#undef PH_END

  #pragma unroll
  for (int M = 0; M < 8; ++M)
    #pragma unroll
    for (int n2 = 0; n2 < 4; ++n2)
      #pragma unroll
      for (int j = 0; j < 4; ++j) {
        long r = arow + wr * 128 + (M >> 2) * 64 + (M & 3) * 16 + l4 * 4 + j;
        long c = brow + wc * 64 + n2 * 16 + l15;
        C[r * Ndim + c] = acc[M][n2][j];
      }
}

// ---------------- 256x128 2-phase bf16 GEMM (for out-proj; balanced 256-block grid) -----
__global__ __launch_bounds__(512, 2) void gemm256(const u16* __restrict__ A,
                                                  const u16* __restrict__ B,
                                                  float* __restrict__ C,
                                                  int Ndim, int Kdim) {
  extern __shared__ __align__(16) u16 lds[];   // A: 3*16384 u16, B at 49152: 2*8192 u16
  const int tid = threadIdx.x;
  const int lane = tid & 63, wave = tid >> 6;
  const int wr = wave >> 2, wc = wave & 3;
  const int l15 = lane & 15, l4 = lane >> 4;
  const int gx = gridDim.x;
  int lin = blockIdx.y * gx + blockIdx.x;
  const int xcd = lin & 7, ii = lin >> 3;
  const int bx = xcd * (gx >> 3) + (ii >> 3), by = ii & 7;
  const long arow = (long)by * 256, brow = (long)bx * 128;
  const int NT = Kdim >> 6;

  const int rowt = tid >> 3;
  const int koff = ((tid & 7) ^ (rowt & 7)) * 8;
  const u16* gA[4];
  const u16* gB[2];
  #pragma unroll
  for (int r = 0; r < 4; ++r) gA[r] = A + (size_t)(arow + rowt + r * 64) * Kdim + koff;
  #pragma unroll
  for (int r = 0; r < 2; ++r) gB[r] = B + (size_t)(brow + rowt + r * 64) * Kdim + koff;

  auto STA = [&](int u) {
    u16* d = lds + (u % 3) * 16384 + tid * 8;
    #pragma unroll
    for (int r = 0; r < 4; ++r) gload16(gA[r] + (size_t)u * 64, d + r * 4096);
  };
  auto STB = [&](int u) {
    u16* d = lds + 49152 + (u & 1) * 8192 + tid * 8;
    #pragma unroll
    for (int r = 0; r < 2; ++r) gload16(gB[r] + (size_t)u * 64, d + r * 4096);
  };

  bf16x8 af[4][2], bfr[2][2];
  f32x4 acc[8][2] = {};
  int cks[2];
  #pragma unroll
  for (int kc = 0; kc < 2; ++kc) cks[kc] = (((kc * 4 + l4) ^ (l15 & 7)) * 8);

  auto LDA = [&](int u, int mh) {
    const u16* base = lds + (u % 3) * 16384 + (wr * 128 + mh * 64 + l15) * 64;
    #pragma unroll
    for (int m = 0; m < 4; ++m)
      #pragma unroll
      for (int kc = 0; kc < 2; ++kc)
        af[m][kc] = *(const bf16x8*)(base + m * 1024 + cks[kc]);
  };
  auto LDB = [&](int u) {
    const u16* base = lds + 49152 + (u & 1) * 8192 + (wc * 32 + l15) * 64;
    #pragma unroll
    for (int n = 0; n < 2; ++n)
      #pragma unroll
      for (int kc = 0; kc < 2; ++kc)
        bfr[n][kc] = *(const bf16x8*)(base + n * 1024 + cks[kc]);
  };
  auto MM = [&](int mh) {
    #pragma unroll
    for (int kc = 0; kc < 2; ++kc)
      #pragma unroll
      for (int m = 0; m < 4; ++m)
        #pragma unroll
        for (int n = 0; n < 2; ++n)
          acc[mh * 4 + m][n] =
            __builtin_amdgcn_mfma_f32_16x16x32_bf16(af[m][kc], bfr[n][kc],
                                                    acc[mh * 4 + m][n], 0, 0, 0);
  };

#define PH_BEGIN() do { __builtin_amdgcn_s_barrier();                         \
    asm volatile("s_waitcnt lgkmcnt(0)" ::: "memory");                        \
    __builtin_amdgcn_sched_barrier(0);                                        \
    __builtin_amdgcn_s_setprio(1); } while (0)

  STA(0); STB(0); STA(1); STB(1);
  asm volatile("s_waitcnt vmcnt(6)" ::: "memory");
  __builtin_amdgcn_s_barrier();

  for (int u = 0; u < NT; ++u) {
    LDA(u, 0); LDB(u);
    if (u + 2 < NT) STA(u + 2);
    PH_BEGIN(); MM(0);
    __builtin_amdgcn_s_setprio(0);
    __builtin_amdgcn_s_barrier();
    LDA(u, 1);
    if (u + 2 < NT) STB(u + 2);
    PH_BEGIN(); MM(1);
    __builtin_amdgcn_s_setprio(0);
    if (u + 2 < NT) { asm volatile("s_waitcnt vmcnt(6)" ::: "memory"); }
    else if (u + 1 < NT) { asm volatile("s_waitcnt vmcnt(0)" ::: "memory"); }
    __builtin_amdgcn_s_barrier();
  }
#undef PH_BEGIN

  #pragma unroll
  for (int M = 0; M < 8; ++M)
    #pragma unroll
    for (int n = 0; n < 2; ++n)
      #pragma unroll
      for (int j = 0; j < 4; ++j) {
        long r = arow + wr * 128 + M * 16 + l4 * 4 + j;
        long c = brow + wc * 32 + n * 16 + l15;
        C[r * Ndim + c] = acc[M][n][j];
      }
}

// ---------------- fused per-head LayerNorm + RoPE (+ v passthrough convert) ----------------
__global__ __launch_bounds__(256) void ln_rope_kernel(
    const float* __restrict__ qkv, const int* __restrict__ pos,
    const float* __restrict__ qw, const float* __restrict__ qb2,
    const float* __restrict__ kw, const float* __restrict__ kb2,
    u16* __restrict__ qo, u16* __restrict__ ko, u16* __restrict__ vo, int T) {
  const int hh = blockIdx.x;
  const int t = blockIdx.y * 4 + (threadIdx.x >> 6);
  const int lane = threadIdx.x & 63;
  const float* src = qkv + (size_t)t * 12288 + hh * 128;
  float x1 = src[lane], x2 = src[lane + 64];
  if (hh >= 64) {
    u16* dst = vo + ((size_t)(hh - 64) * T + t) * 128;
    dst[lane] = f2bf(x1); dst[lane + 64] = f2bf(x2);
    return;
  }
  float s = x1 + x2;
  #pragma unroll
  for (int off = 32; off; off >>= 1) s += __shfl_xor(s, off);
  float mu = s * (1.0f / 128.0f);
  float d1 = x1 - mu, d2 = x2 - mu;
  float vs = d1 * d1 + d2 * d2;
  #pragma unroll
  for (int off = 32; off; off >>= 1) vs += __shfl_xor(vs, off);
  float rstd = rsqrtf(vs * (1.0f / 128.0f) + 1e-5f);
  bool isq = hh < 32;
  int hl = isq ? hh : hh - 32;
  const float* w = (isq ? qw : kw) + hl * 128;
  const float* b = (isq ? qb2 : kb2) + hl * 128;
  float y1 = d1 * rstd * w[lane] + b[lane];
  float y2 = d2 * rstd * w[lane + 64] + b[lane + 64];
  float p = (float)pos[t];
  float invf = exp2f((float)lane * (-13.287712379549449f / 64.0f));
  float fr = p * invf;
  float sn, cs;
  __sincosf(fr, &sn, &cs);
  float o1 = y1 * cs - y2 * sn;
  float o2 = y2 * cs + y1 * sn;
  if (isq) {
    const float sc = 0.08838834764831845f;   // 1/sqrt(128) folded into q
    o1 *= sc; o2 *= sc;
    u16* dst = qo + ((size_t)hl * T + t) * 128;
    dst[lane] = f2bf(o1); dst[lane + 64] = f2bf(o2);
  } else {
    u16* dst = ko + ((size_t)hl * T + t) * 128;
    dst[lane] = f2bf(o1); dst[lane + 64] = f2bf(o2);
  }
}

// ---------------- flash attention (causal), bf16 MFMA, online softmax ----------------
__global__ __launch_bounds__(256, 2) void flash_kernel(
    const u16* __restrict__ qb, const u16* __restrict__ kb,
    const u16* __restrict__ vb, u16* __restrict__ attn, int T) {
  __shared__ __align__(16) u16 Ks[64 * 128];
  __shared__ __align__(16) u16 Vt[128 * 64];
  __shared__ __align__(16) u16 Ps[4][32 * 64];
  const int tid = threadIdx.x;
  const int lane = tid & 63, wave = tid >> 6;
  const int l15 = lane & 15, l4 = lane >> 4;
  const int h = blockIdx.y;
  const int qbase = blockIdx.x * 128;
  const int qrow0 = qbase + wave * 32;
  const u16* Q  = qb + (size_t)h * T * 128;
  const u16* Kp = kb + (size_t)h * T * 128;
  const u16* Vp = vb + (size_t)h * T * 128;
  const int rK0 = tid >> 4, d8k = (tid & 15) * 8;

  bf16x8 qf[2][4];
  #pragma unroll
  for (int mi = 0; mi < 2; ++mi)
    #pragma unroll
    for (int kc = 0; kc < 4; ++kc)
      qf[mi][kc] = *(const bf16x8*)&Q[(size_t)(qrow0 + mi * 16 + l15) * 128 + kc * 32 + l4 * 8];

  float m_st[2][4], l_st[2][4];
  f32x4 o[2][8] = {};
  #pragma unroll
  for (int mi = 0; mi < 2; ++mi)
    #pragma unroll
    for (int j = 0; j < 4; ++j) { m_st[mi][j] = -1e30f; l_st[mi][j] = 0.0f; }

  const int ntile = (qbase + 128) / 64;
  uint4 kr[4], vr[4];
  #pragma unroll
  for (int c = 0; c < 4; ++c) {
    kr[c] = *(const uint4*)&Kp[(size_t)(rK0 + 16 * c) * 128 + d8k];
    vr[c] = *(const uint4*)&Vp[(size_t)lane * 128 + (wave + 4 * c) * 8];
  }
  for (int kt = 0; kt < ntile; ++kt) {
    const int kbase = kt * 64;
    #pragma unroll
    for (int c = 0; c < 4; ++c) {
      *(uint4*)&Ks[swz128i(rK0 + 16 * c, d8k)] = kr[c];
      const u16* pv = (const u16*)&vr[c];
      int dv = (wave + 4 * c) * 8;
      #pragma unroll
      for (int j = 0; j < 8; ++j) Vt[swz64i(dv + j, lane)] = pv[j];
    }
    __syncthreads();
    if (kt + 1 < ntile) {
      const int nb = kbase + 64;
      #pragma unroll
      for (int c = 0; c < 4; ++c) {
        kr[c] = *(const uint4*)&Kp[(size_t)(nb + rK0 + 16 * c) * 128 + d8k];
        vr[c] = *(const uint4*)&Vp[(size_t)(nb + lane) * 128 + (wave + 4 * c) * 8];
      }
    }
    if (kbase <= qrow0 + 31) {
      f32x4 s[2][4] = {};
      __builtin_amdgcn_s_setprio(1);
      #pragma unroll
      for (int kc = 0; kc < 4; ++kc)
        #pragma unroll
        for (int nj = 0; nj < 4; ++nj) {
          bf16x8 kf = *(const bf16x8*)&Ks[swz128i(nj * 16 + l15, kc * 32 + l4 * 8)];
          #pragma unroll
          for (int mi = 0; mi < 2; ++mi)
            s[mi][nj] = __builtin_amdgcn_mfma_f32_16x16x32_bf16(qf[mi][kc], kf, s[mi][nj], 0, 0, 0);
        }
      __builtin_amdgcn_s_setprio(0);
      if (kbase + 63 > qrow0) {
        #pragma unroll
        for (int mi = 0; mi < 2; ++mi)
          #pragma unroll
          for (int nj = 0; nj < 4; ++nj)
            #pragma unroll
            for (int j = 0; j < 4; ++j) {
              int r = qrow0 + mi * 16 + l4 * 4 + j;
              int cc = kbase + nj * 16 + l15;
              if (cc > r) s[mi][nj][j] = -1e30f;
            }
      }
      float vmax[2][4];
      float dmax = -1e30f;
      #pragma unroll
      for (int mi = 0; mi < 2; ++mi)
        #pragma unroll
        for (int j = 0; j < 4; ++j) {
          float v = fmaxf(fmaxf(s[mi][0][j], s[mi][1][j]), fmaxf(s[mi][2][j], s[mi][3][j]));
          #pragma unroll
          for (int off = 1; off < 16; off <<= 1) v = fmaxf(v, __shfl_xor(v, off));
          vmax[mi][j] = v;
          dmax = fmaxf(dmax, v - m_st[mi][j]);
        }
      if (!__all(dmax <= 8.0f)) {
        #pragma unroll
        for (int mi = 0; mi < 2; ++mi)
          #pragma unroll
          for (int j = 0; j < 4; ++j) {
            float mn = fmaxf(m_st[mi][j], vmax[mi][j]);
            float scl = __expf(m_st[mi][j] - mn);
            m_st[mi][j] = mn;
            l_st[mi][j] *= scl;
            #pragma unroll
            for (int nf = 0; nf < 8; ++nf) o[mi][nf][j] *= scl;
          }
      }
      #pragma unroll
      for (int mi = 0; mi < 2; ++mi) {
        float sum[4] = {0.f, 0.f, 0.f, 0.f};
        #pragma unroll
        for (int nj = 0; nj < 4; ++nj)
          #pragma unroll
          for (int j = 0; j < 4; ++j) {
            float p = __expf(s[mi][nj][j] - m_st[mi][j]);
            s[mi][nj][j] = p;
            sum[j] += p;
          }
        #pragma unroll
        for (int j = 0; j < 4; ++j) {
          #pragma unroll
          for (int off = 1; off < 16; off <<= 1) sum[j] += __shfl_xor(sum[j], off);
          l_st[mi][j] += sum[j];
        }
        #pragma unroll
        for (int nj = 0; nj < 4; ++nj)
          #pragma unroll
          for (int j = 0; j < 4; ++j)
            Ps[wave][swz64i(mi * 16 + l4 * 4 + j, nj * 16 + l15)] = f2bf(s[mi][nj][j]);
      }
      asm volatile("s_waitcnt lgkmcnt(0)" ::: "memory");
      __builtin_amdgcn_sched_barrier(0);
      __builtin_amdgcn_s_setprio(1);
      #pragma unroll
      for (int mi = 0; mi < 2; ++mi)
        #pragma unroll
        for (int kc = 0; kc < 2; ++kc) {
          bf16x8 pf = *(const bf16x8*)&Ps[wave][swz64i(mi * 16 + l15, kc * 32 + l4 * 8)];
          #pragma unroll
          for (int nf = 0; nf < 8; ++nf) {
            bf16x8 vf = *(const bf16x8*)&Vt[swz64i(nf * 16 + l15, kc * 32 + l4 * 8)];
            o[mi][nf] = __builtin_amdgcn_mfma_f32_16x16x32_bf16(pf, vf, o[mi][nf], 0, 0, 0);
          }
        }
      __builtin_amdgcn_s_setprio(0);
    }
    __syncthreads();
  }
  #pragma unroll
  for (int mi = 0; mi < 2; ++mi) {
    float rl[4];
    #pragma unroll
    for (int j = 0; j < 4; ++j) rl[j] = 1.0f / l_st[mi][j];
    #pragma unroll
    for (int nf = 0; nf < 8; ++nf)
      #pragma unroll
      for (int j = 0; j < 4; ++j) {
        int r = qrow0 + mi * 16 + l4 * 4 + j;
        int cc = h * 128 + nf * 16 + l15;
        attn[(size_t)r * 4096 + cc] = f2bf(o[mi][nf][j] * rl[j]);
      }
  }
}

// ---------------- launch ----------------
extern "C" void kernel_launch(void* const* d_in, const int* in_sizes, int n_in,
                              void* d_out, int out_size, void* d_ws, size_t ws_size,
                              hipStream_t stream) {
  const int* positions = (const int*)d_in[0];
  const float* hidden  = (const float*)d_in[1];
  const float* w_qkv   = (const float*)d_in[2];
  const float* w_o     = (const float*)d_in[3];
  const float* qnw     = (const float*)d_in[4];
  const float* qnb     = (const float*)d_in[5];
  const float* knw     = (const float*)d_in[6];
  const float* knb     = (const float*)d_in[7];
  float* out = (float*)d_out;

  const int T = in_sizes[0];           // 2048
  const int HID = 4096, NQKV = 12288, H = 32;

  char* ws = (char*)d_ws;
  u16* hid_bf  = (u16*)ws;
  u16* wreg    = (u16*)(ws + (size_t)T * HID * 2);
  float* qkv_f = (float*)(ws + (size_t)T * HID * 2 + (size_t)NQKV * HID * 2);

  u16* q_bf  = wreg;                                 // [H][T][128]
  u16* k_bf  = q_bf + (size_t)H * T * 128;           // [H][T][128]
  u16* v_bf  = k_bf + (size_t)H * T * 128;           // [H][T][128]
  u16* at_bf = v_bf + (size_t)H * T * 128;           // [T][H*128]
  u16* wo_bf = at_bf + (size_t)T * 4096;             // [4096][4096]

  hipFuncSetAttribute(reinterpret_cast<const void*>(&gemm256sq),
                      hipFuncAttributeMaxDynamicSharedMemorySize, 131072);
  hipFuncSetAttribute(reinterpret_cast<const void*>(&gemm256),
                      hipFuncAttributeMaxDynamicSharedMemorySize, 131072);

  cvt_bf16_kernel<<<2048, 256, 0, stream>>>(hidden, hid_bf, (long)T * HID / 4);
  cvt_bf16_kernel<<<4096, 256, 0, stream>>>(w_qkv, wreg, (long)NQKV * HID / 4);
  gemm256sq<<<dim3(NQKV / 256, T / 256), 512, 131072, stream>>>(hid_bf, wreg, qkv_f, NQKV, HID);
  ln_rope_kernel<<<dim3(96, T / 4), 256, 0, stream>>>(qkv_f, positions, qnw, qnb, knw, knb,
                                                      q_bf, k_bf, v_bf, T);
  cvt_bf16_kernel<<<2048, 256, 0, stream>>>(w_o, wo_bf, (long)HID * HID / 4);
  flash_kernel<<<dim3(T / 128, H), 256, 0, stream>>>(q_bf, k_bf, v_bf, at_bf, T);
  gemm256<<<dim3(HID / 128, T / 256), 512, 131072, stream>>>(at_bf, wo_bf, out, HID, HID);
}

// Round 8
// 548.100 us; speedup vs baseline: 1.0379x; 1.0379x over previous
//
#include <hip/hip_runtime.h>
#include <cstdint>

typedef unsigned short u16;
typedef __attribute__((ext_vector_type(8))) __bf16 bf16x8;
typedef __attribute__((ext_vector_type(4))) float f32x4;

__device__ __forceinline__ u16 f2bf(float f) {
  unsigned int u = __builtin_bit_cast(unsigned int, f);
  unsigned int r = (u + 0x7fffu + ((u >> 16) & 1u)) >> 16;
  return (u16)r;
}

// async global->LDS, 16B per lane. LDS dest must be linear in lane (wave base + lane*16).
__device__ __forceinline__ void gload16(const u16* g, u16* l) {
  __builtin_amdgcn_global_load_lds((const __attribute__((address_space(1))) void*)g,
                                   (__attribute__((address_space(3))) void*)l, 16, 0, 0);
}

// XOR-swizzle helpers for flash kernel LDS.
__device__ __forceinline__ int swz64i(int row, int col) {   // 64 u16 cols per row
  return row * 64 + (((col & 0x38) ^ ((row & 7) << 3)) | (col & 7));
}
__device__ __forceinline__ int swz128i(int row, int col) {  // 128 u16 cols per row
  return row * 128 + (((col & 0x78) ^ ((row & 7) << 3)) | (col & 7));
}

// ---------------- fp32 -> bf16 conversion ----------------
__global__ __launch_bounds__(256) void cvt_bf16_kernel(const float* __restrict__ in,
                                                       u16* __restrict__ out, long n4) {
  long i = (long)blockIdx.x * 256 + threadIdx.x;
  long stride = (long)gridDim.x * 256;
  const float4* in4 = (const float4*)in;
  uint2* out2 = (uint2*)out;
  for (long k = i; k < n4; k += stride) {
    float4 v = in4[k];
    uint2 o;
    o.x = (unsigned int)f2bf(v.x) | ((unsigned int)f2bf(v.y) << 16);
    o.y = (unsigned int)f2bf(v.z) | ((unsigned int)f2bf(v.w) << 16);
    out2[k] = o;
  }
}

// ---------------- 256x192 3-phase bf16 GEMM (QKV: grid 64x8 = 512 = 2.0 exact rounds) ----
// C[M][N] = A[M][K] * B[N][K]^T, fp32 C. BK=64, 512 thr, 8 waves 2Mx4N, wave = 128x48.
// A frags held in regs across the K-tile (af[8][2], read once at ph1); acc[8][3].
// LDS 112KiB: A dbuf 2x32KB @0, B dbuf 2x24KB @32768(u16).
// Phases: ph1 {LDA 16 + LDB(0) 2 | STB(u+1)}, ph2 {LDB(1) | STA(u+2)}, ph3 {LDB(2) | drain}.
// vmcnt: ph3 steady = keep A(u+2) -> vmcnt(4); tails vmcnt(0).
// Requires gridDim.x % 8 == 0, gridDim.y == 8, K % 64 == 0, K/64 >= 3.
__global__ __launch_bounds__(512, 2) void gemm192(const u16* __restrict__ A,
                                                  const u16* __restrict__ B,
                                                  float* __restrict__ C,
                                                  int Ndim, int Kdim) {
  extern __shared__ __align__(16) u16 lds[];
  const int tid = threadIdx.x;
  const int lane = tid & 63, wave = tid >> 6;
  const int wr = wave >> 2, wc = wave & 3;
  const int l15 = lane & 15, l4 = lane >> 4;
  const int gx = gridDim.x;
  int lin = blockIdx.y * gx + blockIdx.x;
  const int xcd = lin & 7, ii = lin >> 3;
  const int bx = xcd * (gx >> 3) + (ii >> 3), by = ii & 7;
  const long arow = (long)by * 256, brow = (long)bx * 192;
  const int NT = Kdim >> 6;

  const int rowt = tid >> 3;
  const int koff = ((tid & 7) ^ (rowt & 7)) * 8;
  const u16* gA[4];
  const u16* gB[3];
  #pragma unroll
  for (int r = 0; r < 4; ++r) gA[r] = A + (size_t)(arow + rowt + r * 64) * Kdim + koff;
  #pragma unroll
  for (int r = 0; r < 3; ++r) gB[r] = B + (size_t)(brow + rowt + r * 64) * Kdim + koff;
  u16* const ldsB = lds + 32768;

  auto STA = [&](int u) {   // 4 gloads -> A-buf u&1
    u16* d = lds + (u & 1) * 16384 + tid * 8;
    #pragma unroll
    for (int r = 0; r < 4; ++r) gload16(gA[r] + (size_t)u * 64, d + r * 4096);
  };
  auto STB = [&](int u) {   // 3 gloads -> B-buf u&1
    u16* d = ldsB + (u & 1) * 12288 + tid * 8;
    #pragma unroll
    for (int r = 0; r < 3; ++r) gload16(gB[r] + (size_t)u * 64, d + r * 4096);
  };

  bf16x8 af[8][2], bfr[2];
  f32x4 acc[8][3] = {};
  int cks[2];
  #pragma unroll
  for (int kc = 0; kc < 2; ++kc) cks[kc] = (((kc * 4 + l4) ^ (l15 & 7)) * 8);

  auto LDA = [&](int u) {   // 16 x ds_read_b128: all 8 m-frags, both kc
    const u16* base = lds + (u & 1) * 16384 + (wr * 128 + l15) * 64;
    #pragma unroll
    for (int m = 0; m < 8; ++m)
      #pragma unroll
      for (int kc = 0; kc < 2; ++kc)
        af[m][kc] = *(const bf16x8*)(base + m * 1024 + cks[kc]);
  };
  auto LDB = [&](int u, int nh) {   // 2 x ds_read_b128: n-frag nh, both kc
    const u16* base = ldsB + (u & 1) * 12288 + (wc * 48 + nh * 16 + l15) * 64;
    #pragma unroll
    for (int kc = 0; kc < 2; ++kc)
      bfr[kc] = *(const bf16x8*)(base + cks[kc]);
  };
  auto MMQ = [&](int nh) {   // 16 MFMA, kc outermost: acc reuse 8 apart
    #pragma unroll
    for (int kc = 0; kc < 2; ++kc)
      #pragma unroll
      for (int m = 0; m < 8; ++m)
        acc[m][nh] = __builtin_amdgcn_mfma_f32_16x16x32_bf16(af[m][kc], bfr[kc],
                                                             acc[m][nh], 0, 0, 0);
  };

#define PH_BEGIN() do { __builtin_amdgcn_s_barrier();                         \
    asm volatile("s_waitcnt lgkmcnt(0)" ::: "memory");                        \
    __builtin_amdgcn_sched_barrier(0);                                        \
    __builtin_amdgcn_s_setprio(1); } while (0)
#define PH_END() do { __builtin_amdgcn_s_setprio(0);                          \
    __builtin_amdgcn_s_barrier(); } while (0)

  // prologue: A0,B0 -> buf0; A1 -> buf1. Drain A0+B0 (leave A1's 4 in flight).
  STA(0); STB(0); STA(1);
  asm volatile("s_waitcnt vmcnt(4)" ::: "memory");
  __builtin_amdgcn_s_barrier();

  for (int u = 0; u < NT; ++u) {
    // ph1: all A frags + B frag 0 ; stage next B
    LDA(u); LDB(u, 0);
    if (u + 1 < NT) STB(u + 1);
    PH_BEGIN(); MMQ(0); PH_END();
    // ph2: B frag 1 ; stage A(u+2) (A-buf[u&1] reads finished at ph1 end)
    LDB(u, 1);
    if (u + 2 < NT) STA(u + 2);
    PH_BEGIN(); MMQ(1); PH_END();
    // ph3: B frag 2 ; drain for next tile
    LDB(u, 2);
    PH_BEGIN(); MMQ(2);
    __builtin_amdgcn_s_setprio(0);
    if (u + 2 < NT) { asm volatile("s_waitcnt vmcnt(4)" ::: "memory"); }
    else            { asm volatile("s_waitcnt vmcnt(0)" ::: "memory"); }
    __builtin_amdgcn_s_barrier();
  }
#undef PH_BEGIN
#undef PH_END

  #pragma unroll
  for (int m = 0; m < 8; ++m)
    #pragma unroll
    for (int nh = 0; nh < 3; ++nh)
      #pragma unroll
      for (int j = 0; j < 4; ++j) {
        long r = arow + wr * 128 + m * 16 + l4 * 4 + j;
        long c = brow + wc * 48 + nh * 16 + l15;
        C[r * Ndim + c] = acc[m][nh][j];
      }
}

// ---------------- 256x128 2-phase bf16 GEMM (out-proj; 256-block balanced grid) -----
__global__ __launch_bounds__(512, 2) void gemm256(const u16* __restrict__ A,
                                                  const u16* __restrict__ B,
                                                  float* __restrict__ C,
                                                  int Ndim, int Kdim) {
  extern __shared__ __align__(16) u16 lds[];   // A: 3*16384 u16, B at 49152: 2*8192 u16
  const int tid = threadIdx.x;
  const int lane = tid & 63, wave = tid >> 6;
  const int wr = wave >> 2, wc = wave & 3;
  const int l15 = lane & 15, l4 = lane >> 4;
  const int gx = gridDim.x;
  int lin = blockIdx.y * gx + blockIdx.x;
  const int xcd = lin & 7, ii = lin >> 3;
  const int bx = xcd * (gx >> 3) + (ii >> 3), by = ii & 7;
  const long arow = (long)by * 256, brow = (long)bx * 128;
  const int NT = Kdim >> 6;

  const int rowt = tid >> 3;
  const int koff = ((tid & 7) ^ (rowt & 7)) * 8;
  const u16* gA[4];
  const u16* gB[2];
  #pragma unroll
  for (int r = 0; r < 4; ++r) gA[r] = A + (size_t)(arow + rowt + r * 64) * Kdim + koff;
  #pragma unroll
  for (int r = 0; r < 2; ++r) gB[r] = B + (size_t)(brow + rowt + r * 64) * Kdim + koff;

  auto STA = [&](int u) {
    u16* d = lds + (u % 3) * 16384 + tid * 8;
    #pragma unroll
    for (int r = 0; r < 4; ++r) gload16(gA[r] + (size_t)u * 64, d + r * 4096);
  };
  auto STB = [&](int u) {
    u16* d = lds + 49152 + (u & 1) * 8192 + tid * 8;
    #pragma unroll
    for (int r = 0; r < 2; ++r) gload16(gB[r] + (size_t)u * 64, d + r * 4096);
  };

  bf16x8 af[4][2], bfr[2][2];
  f32x4 acc[8][2] = {};
  int cks[2];
  #pragma unroll
  for (int kc = 0; kc < 2; ++kc) cks[kc] = (((kc * 4 + l4) ^ (l15 & 7)) * 8);

  auto LDA = [&](int u, int mh) {
    const u16* base = lds + (u % 3) * 16384 + (wr * 128 + mh * 64 + l15) * 64;
    #pragma unroll
    for (int m = 0; m < 4; ++m)
      #pragma unroll
      for (int kc = 0; kc < 2; ++kc)
        af[m][kc] = *(const bf16x8*)(base + m * 1024 + cks[kc]);
  };
  auto LDB = [&](int u) {
    const u16* base = lds + 49152 + (u & 1) * 8192 + (wc * 32 + l15) * 64;
    #pragma unroll
    for (int n = 0; n < 2; ++n)
      #pragma unroll
      for (int kc = 0; kc < 2; ++kc)
        bfr[n][kc] = *(const bf16x8*)(base + n * 1024 + cks[kc]);
  };
  auto MM = [&](int mh) {
    #pragma unroll
    for (int kc = 0; kc < 2; ++kc)
      #pragma unroll
      for (int m = 0; m < 4; ++m)
        #pragma unroll
        for (int n = 0; n < 2; ++n)
          acc[mh * 4 + m][n] =
            __builtin_amdgcn_mfma_f32_16x16x32_bf16(af[m][kc], bfr[n][kc],
                                                    acc[mh * 4 + m][n], 0, 0, 0);
  };

#define PH_BEGIN() do { __builtin_amdgcn_s_barrier();                         \
    asm volatile("s_waitcnt lgkmcnt(0)" ::: "memory");                        \
    __builtin_amdgcn_sched_barrier(0);                                        \
    __builtin_amdgcn_s_setprio(1); } while (0)

  STA(0); STB(0); STA(1); STB(1);
  asm volatile("s_waitcnt vmcnt(6)" ::: "memory");
  __builtin_amdgcn_s_barrier();

  for (int u = 0; u < NT; ++u) {
    LDA(u, 0); LDB(u);
    if (u + 2 < NT) STA(u + 2);
    PH_BEGIN(); MM(0);
    __builtin_amdgcn_s_setprio(0);
    __builtin_amdgcn_s_barrier();
    LDA(u, 1);
    if (u + 2 < NT) STB(u + 2);
    PH_BEGIN(); MM(1);
    __builtin_amdgcn_s_setprio(0);
    if (u + 2 < NT) { asm volatile("s_waitcnt vmcnt(6)" ::: "memory"); }
    else if (u + 1 < NT) { asm volatile("s_waitcnt vmcnt(0)" ::: "memory"); }
    __builtin_amdgcn_s_barrier();
  }
#undef PH_BEGIN

  #pragma unroll
  for (int M = 0; M < 8; ++M)
    #pragma unroll
    for (int n = 0; n < 2; ++n)
      #pragma unroll
      for (int j = 0; j < 4; ++j) {
        long r = arow + wr * 128 + M * 16 + l4 * 4 + j;
        long c = brow + wc * 32 + n * 16 + l15;
        C[r * Ndim + c] = acc[M][n][j];
      }
}

// ---------------- fused per-head LayerNorm + RoPE (+ v passthrough convert) ----------------
__global__ __launch_bounds__(256) void ln_rope_kernel(
    const float* __restrict__ qkv, const int* __restrict__ pos,
    const float* __restrict__ qw, const float* __restrict__ qb2,
    const float* __restrict__ kw, const float* __restrict__ kb2,
    u16* __restrict__ qo, u16* __restrict__ ko, u16* __restrict__ vo, int T) {
  const int hh = blockIdx.x;
  const int t = blockIdx.y * 4 + (threadIdx.x >> 6);
  const int lane = threadIdx.x & 63;
  const float* src = qkv + (size_t)t * 12288 + hh * 128;
  float x1 = src[lane], x2 = src[lane + 64];
  if (hh >= 64) {
    u16* dst = vo + ((size_t)(hh - 64) * T + t) * 128;
    dst[lane] = f2bf(x1); dst[lane + 64] = f2bf(x2);
    return;
  }
  float s = x1 + x2;
  #pragma unroll
  for (int off = 32; off; off >>= 1) s += __shfl_xor(s, off);
  float mu = s * (1.0f / 128.0f);
  float d1 = x1 - mu, d2 = x2 - mu;
  float vs = d1 * d1 + d2 * d2;
  #pragma unroll
  for (int off = 32; off; off >>= 1) vs += __shfl_xor(vs, off);
  float rstd = rsqrtf(vs * (1.0f / 128.0f) + 1e-5f);
  bool isq = hh < 32;
  int hl = isq ? hh : hh - 32;
  const float* w = (isq ? qw : kw) + hl * 128;
  const float* b = (isq ? qb2 : kb2) + hl * 128;
  float y1 = d1 * rstd * w[lane] + b[lane];
  float y2 = d2 * rstd * w[lane + 64] + b[lane + 64];
  float p = (float)pos[t];
  float invf = exp2f((float)lane * (-13.287712379549449f / 64.0f));
  float fr = p * invf;
  float sn, cs;
  __sincosf(fr, &sn, &cs);
  float o1 = y1 * cs - y2 * sn;
  float o2 = y2 * cs + y1 * sn;
  if (isq) {
    const float sc = 0.08838834764831845f;   // 1/sqrt(128) folded into q
    o1 *= sc; o2 *= sc;
    u16* dst = qo + ((size_t)hl * T + t) * 128;
    dst[lane] = f2bf(o1); dst[lane + 64] = f2bf(o2);
  } else {
    u16* dst = ko + ((size_t)hl * T + t) * 128;
    dst[lane] = f2bf(o1); dst[lane + 64] = f2bf(o2);
  }
}

// ---------------- flash attention (causal), bf16 MFMA, online softmax ----------------
__global__ __launch_bounds__(256, 2) void flash_kernel(
    const u16* __restrict__ qb, const u16* __restrict__ kb,
    const u16* __restrict__ vb, u16* __restrict__ attn, int T) {
  __shared__ __align__(16) u16 Ks[64 * 128];
  __shared__ __align__(16) u16 Vt[128 * 64];
  __shared__ __align__(16) u16 Ps[4][32 * 64];
  const int tid = threadIdx.x;
  const int lane = tid & 63, wave = tid >> 6;
  const int l15 = lane & 15, l4 = lane >> 4;
  const int h = blockIdx.y;
  const int qbase = blockIdx.x * 128;
  const int qrow0 = qbase + wave * 32;
  const u16* Q  = qb + (size_t)h * T * 128;
  const u16* Kp = kb + (size_t)h * T * 128;
  const u16* Vp = vb + (size_t)h * T * 128;
  const int rK0 = tid >> 4, d8k = (tid & 15) * 8;

  bf16x8 qf[2][4];
  #pragma unroll
  for (int mi = 0; mi < 2; ++mi)
    #pragma unroll
    for (int kc = 0; kc < 4; ++kc)
      qf[mi][kc] = *(const bf16x8*)&Q[(size_t)(qrow0 + mi * 16 + l15) * 128 + kc * 32 + l4 * 8];

  float m_st[2][4], l_st[2][4];
  f32x4 o[2][8] = {};
  #pragma unroll
  for (int mi = 0; mi < 2; ++mi)
    #pragma unroll
    for (int j = 0; j < 4; ++j) { m_st[mi][j] = -1e30f; l_st[mi][j] = 0.0f; }

  const int ntile = (qbase + 128) / 64;
  uint4 kr[4], vr[4];
  #pragma unroll
  for (int c = 0; c < 4; ++c) {
    kr[c] = *(const uint4*)&Kp[(size_t)(rK0 + 16 * c) * 128 + d8k];
    vr[c] = *(const uint4*)&Vp[(size_t)lane * 128 + (wave + 4 * c) * 8];
  }
  for (int kt = 0; kt < ntile; ++kt) {
    const int kbase = kt * 64;
    #pragma unroll
    for (int c = 0; c < 4; ++c) {
      *(uint4*)&Ks[swz128i(rK0 + 16 * c, d8k)] = kr[c];
      const u16* pv = (const u16*)&vr[c];
      int dv = (wave + 4 * c) * 8;
      #pragma unroll
      for (int j = 0; j < 8; ++j) Vt[swz64i(dv + j, lane)] = pv[j];
    }
    __syncthreads();
    if (kt + 1 < ntile) {
      const int nb = kbase + 64;
      #pragma unroll
      for (int c = 0; c < 4; ++c) {
        kr[c] = *(const uint4*)&Kp[(size_t)(nb + rK0 + 16 * c) * 128 + d8k];
        vr[c] = *(const uint4*)&Vp[(size_t)(nb + lane) * 128 + (wave + 4 * c) * 8];
      }
    }
    if (kbase <= qrow0 + 31) {
      f32x4 s[2][4] = {};
      __builtin_amdgcn_s_setprio(1);
      #pragma unroll
      for (int kc = 0; kc < 4; ++kc)
        #pragma unroll
        for (int nj = 0; nj < 4; ++nj) {
          bf16x8 kf = *(const bf16x8*)&Ks[swz128i(nj * 16 + l15, kc * 32 + l4 * 8)];
          #pragma unroll
          for (int mi = 0; mi < 2; ++mi)
            s[mi][nj] = __builtin_amdgcn_mfma_f32_16x16x32_bf16(qf[mi][kc], kf, s[mi][nj], 0, 0, 0);
        }
      __builtin_amdgcn_s_setprio(0);
      if (kbase + 63 > qrow0) {
        #pragma unroll
        for (int mi = 0; mi < 2; ++mi)
          #pragma unroll
          for (int nj = 0; nj < 4; ++nj)
            #pragma unroll
            for (int j = 0; j < 4; ++j) {
              int r = qrow0 + mi * 16 + l4 * 4 + j;
              int cc = kbase + nj * 16 + l15;
              if (cc > r) s[mi][nj][j] = -1e30f;
            }
      }
      float vmax[2][4];
      float dmax = -1e30f;
      #pragma unroll
      for (int mi = 0; mi < 2; ++mi)
        #pragma unroll
        for (int j = 0; j < 4; ++j) {
          float v = fmaxf(fmaxf(s[mi][0][j], s[mi][1][j]), fmaxf(s[mi][2][j], s[mi][3][j]));
          #pragma unroll
          for (int off = 1; off < 16; off <<= 1) v = fmaxf(v, __shfl_xor(v, off));
          vmax[mi][j] = v;
          dmax = fmaxf(dmax, v - m_st[mi][j]);
        }
      if (!__all(dmax <= 8.0f)) {
        #pragma unroll
        for (int mi = 0; mi < 2; ++mi)
          #pragma unroll
          for (int j = 0; j < 4; ++j) {
            float mn = fmaxf(m_st[mi][j], vmax[mi][j]);
            float scl = __expf(m_st[mi][j] - mn);
            m_st[mi][j] = mn;
            l_st[mi][j] *= scl;
            #pragma unroll
            for (int nf = 0; nf < 8; ++nf) o[mi][nf][j] *= scl;
          }
      }
      #pragma unroll
      for (int mi = 0; mi < 2; ++mi) {
        float sum[4] = {0.f, 0.f, 0.f, 0.f};
        #pragma unroll
        for (int nj = 0; nj < 4; ++nj)
          #pragma unroll
          for (int j = 0; j < 4; ++j) {
            float p = __expf(s[mi][nj][j] - m_st[mi][j]);
            s[mi][nj][j] = p;
            sum[j] += p;
          }
        #pragma unroll
        for (int j = 0; j < 4; ++j) {
          #pragma unroll
          for (int off = 1; off < 16; off <<= 1) sum[j] += __shfl_xor(sum[j], off);
          l_st[mi][j] += sum[j];
        }
        #pragma unroll
        for (int nj = 0; nj < 4; ++nj)
          #pragma unroll
          for (int j = 0; j < 4; ++j)
            Ps[wave][swz64i(mi * 16 + l4 * 4 + j, nj * 16 + l15)] = f2bf(s[mi][nj][j]);
      }
      asm volatile("s_waitcnt lgkmcnt(0)" ::: "memory");
      __builtin_amdgcn_sched_barrier(0);
      __builtin_amdgcn_s_setprio(1);
      #pragma unroll
      for (int mi = 0; mi < 2; ++mi)
        #pragma unroll
        for (int kc = 0; kc < 2; ++kc) {
          bf16x8 pf = *(const bf16x8*)&Ps[wave][swz64i(mi * 16 + l15, kc * 32 + l4 * 8)];
          #pragma unroll
          for (int nf = 0; nf < 8; ++nf) {
            bf16x8 vf = *(const bf16x8*)&Vt[swz64i(nf * 16 + l15, kc * 32 + l4 * 8)];
            o[mi][nf] = __builtin_amdgcn_mfma_f32_16x16x32_bf16(pf, vf, o[mi][nf], 0, 0, 0);
          }
        }
      __builtin_amdgcn_s_setprio(0);
    }
    __syncthreads();
  }
  #pragma unroll
  for (int mi = 0; mi < 2; ++mi) {
    float rl[4];
    #pragma unroll
    for (int j = 0; j < 4; ++j) rl[j] = 1.0f / l_st[mi][j];
    #pragma unroll
    for (int nf = 0; nf < 8; ++nf)
      #pragma unroll
      for (int j = 0; j < 4; ++j) {
        int r = qrow0 + mi * 16 + l4 * 4 + j;
        int cc = h * 128 + nf * 16 + l15;
        attn[(size_t)r * 4096 + cc] = f2bf(o[mi][nf][j] * rl[j]);
      }
  }
}

// ---------------- launch ----------------
extern "C" void kernel_launch(void* const* d_in, const int* in_sizes, int n_in,
                              void* d_out, int out_size, void* d_ws, size_t ws_size,
                              hipStream_t stream) {
  const int* positions = (const int*)d_in[0];
  const float* hidden  = (const float*)d_in[1];
  const float* w_qkv   = (const float*)d_in[2];
  const float* w_o     = (const float*)d_in[3];
  const float* qnw     = (const float*)d_in[4];
  const float* qnb     = (const float*)d_in[5];
  const float* knw     = (const float*)d_in[6];
  const float* knb     = (const float*)d_in[7];
  float* out = (float*)d_out;

  const int T = in_sizes[0];           // 2048
  const int HID = 4096, NQKV = 12288, H = 32;

  char* ws = (char*)d_ws;
  u16* hid_bf  = (u16*)ws;
  u16* wreg    = (u16*)(ws + (size_t)T * HID * 2);
  float* qkv_f = (float*)(ws + (size_t)T * HID * 2 + (size_t)NQKV * HID * 2);

  u16* q_bf  = wreg;                                 // [H][T][128]
  u16* k_bf  = q_bf + (size_t)H * T * 128;           // [H][T][128]
  u16* v_bf  = k_bf + (size_t)H * T * 128;           // [H][T][128]
  u16* at_bf = v_bf + (size_t)H * T * 128;           // [T][H*128]
  u16* wo_bf = at_bf + (size_t)T * 4096;             // [4096][4096]

  hipFuncSetAttribute(reinterpret_cast<const void*>(&gemm192),
                      hipFuncAttributeMaxDynamicSharedMemorySize, 114688);
  hipFuncSetAttribute(reinterpret_cast<const void*>(&gemm256),
                      hipFuncAttributeMaxDynamicSharedMemorySize, 131072);

  cvt_bf16_kernel<<<2048, 256, 0, stream>>>(hidden, hid_bf, (long)T * HID / 4);
  cvt_bf16_kernel<<<4096, 256, 0, stream>>>(w_qkv, wreg, (long)NQKV * HID / 4);
  gemm192<<<dim3(NQKV / 192, T / 256), 512, 114688, stream>>>(hid_bf, wreg, qkv_f, NQKV, HID);
  ln_rope_kernel<<<dim3(96, T / 4), 256, 0, stream>>>(qkv_f, positions, qnw, qnb, knw, knb,
                                                      q_bf, k_bf, v_bf, T);
  cvt_bf16_kernel<<<2048, 256, 0, stream>>>(w_o, wo_bf, (long)HID * HID / 4);
  flash_kernel<<<dim3(T / 128, H), 256, 0, stream>>>(q_bf, k_bf, v_bf, at_bf, T);
  gemm256<<<dim3(HID / 128, T / 256), 512, 131072, stream>>>(at_bf, wo_bf, out, HID, HID);
}

// Round 9
// 543.941 us; speedup vs baseline: 1.0459x; 1.0076x over previous
//
#include <hip/hip_runtime.h>
#include <cstdint>

typedef unsigned short u16;
typedef __attribute__((ext_vector_type(8))) __bf16 bf16x8;
typedef __attribute__((ext_vector_type(4))) float f32x4;

__device__ __forceinline__ u16 f2bf(float f) {
  unsigned int u = __builtin_bit_cast(unsigned int, f);
  unsigned int r = (u + 0x7fffu + ((u >> 16) & 1u)) >> 16;
  return (u16)r;
}
__device__ __forceinline__ float bf2f(u16 u) {
  return __builtin_bit_cast(float, (unsigned int)u << 16);
}

// async global->LDS, 16B per lane. LDS dest must be linear in lane (wave base + lane*16).
__device__ __forceinline__ void gload16(const u16* g, u16* l) {
  __builtin_amdgcn_global_load_lds((const __attribute__((address_space(1))) void*)g,
                                   (__attribute__((address_space(3))) void*)l, 16, 0, 0);
}

// XOR-swizzle helpers for flash kernel LDS.
__device__ __forceinline__ int swz64i(int row, int col) {   // 64 u16 cols per row
  return row * 64 + (((col & 0x38) ^ ((row & 7) << 3)) | (col & 7));
}
__device__ __forceinline__ int swz128i(int row, int col) {  // 128 u16 cols per row
  return row * 128 + (((col & 0x78) ^ ((row & 7) << 3)) | (col & 7));
}

// ---------------- fp32 -> bf16 conversion ----------------
__global__ __launch_bounds__(256) void cvt_bf16_kernel(const float* __restrict__ in,
                                                       u16* __restrict__ out, long n4) {
  long i = (long)blockIdx.x * 256 + threadIdx.x;
  long stride = (long)gridDim.x * 256;
  const float4* in4 = (const float4*)in;
  uint2* out2 = (uint2*)out;
  for (long k = i; k < n4; k += stride) {
    float4 v = in4[k];
    uint2 o;
    o.x = (unsigned int)f2bf(v.x) | ((unsigned int)f2bf(v.y) << 16);
    o.y = (unsigned int)f2bf(v.z) | ((unsigned int)f2bf(v.w) << 16);
    out2[k] = o;
  }
}

// ---------------- 256x192 3-phase bf16 GEMM (QKV; bf16 output) ----
// C[M][N] = A[M][K] * B[N][K]^T, bf16 C. Same engine as R8; only the epilogue changed.
__global__ __launch_bounds__(512, 2) void gemm192(const u16* __restrict__ A,
                                                  const u16* __restrict__ B,
                                                  u16* __restrict__ C,
                                                  int Ndim, int Kdim) {
  extern __shared__ __align__(16) u16 lds[];
  const int tid = threadIdx.x;
  const int lane = tid & 63, wave = tid >> 6;
  const int wr = wave >> 2, wc = wave & 3;
  const int l15 = lane & 15, l4 = lane >> 4;
  const int gx = gridDim.x;
  int lin = blockIdx.y * gx + blockIdx.x;
  const int xcd = lin & 7, ii = lin >> 3;
  const int bx = xcd * (gx >> 3) + (ii >> 3), by = ii & 7;
  const long arow = (long)by * 256, brow = (long)bx * 192;
  const int NT = Kdim >> 6;

  const int rowt = tid >> 3;
  const int koff = ((tid & 7) ^ (rowt & 7)) * 8;
  const u16* gA[4];
  const u16* gB[3];
  #pragma unroll
  for (int r = 0; r < 4; ++r) gA[r] = A + (size_t)(arow + rowt + r * 64) * Kdim + koff;
  #pragma unroll
  for (int r = 0; r < 3; ++r) gB[r] = B + (size_t)(brow + rowt + r * 64) * Kdim + koff;
  u16* const ldsB = lds + 32768;

  auto STA = [&](int u) {
    u16* d = lds + (u & 1) * 16384 + tid * 8;
    #pragma unroll
    for (int r = 0; r < 4; ++r) gload16(gA[r] + (size_t)u * 64, d + r * 4096);
  };
  auto STB = [&](int u) {
    u16* d = ldsB + (u & 1) * 12288 + tid * 8;
    #pragma unroll
    for (int r = 0; r < 3; ++r) gload16(gB[r] + (size_t)u * 64, d + r * 4096);
  };

  bf16x8 af[8][2], bfr[2];
  f32x4 acc[8][3] = {};
  int cks[2];
  #pragma unroll
  for (int kc = 0; kc < 2; ++kc) cks[kc] = (((kc * 4 + l4) ^ (l15 & 7)) * 8);

  auto LDA = [&](int u) {
    const u16* base = lds + (u & 1) * 16384 + (wr * 128 + l15) * 64;
    #pragma unroll
    for (int m = 0; m < 8; ++m)
      #pragma unroll
      for (int kc = 0; kc < 2; ++kc)
        af[m][kc] = *(const bf16x8*)(base + m * 1024 + cks[kc]);
  };
  auto LDB = [&](int u, int nh) {
    const u16* base = ldsB + (u & 1) * 12288 + (wc * 48 + nh * 16 + l15) * 64;
    #pragma unroll
    for (int kc = 0; kc < 2; ++kc)
      bfr[kc] = *(const bf16x8*)(base + cks[kc]);
  };
  auto MMQ = [&](int nh) {
    #pragma unroll
    for (int kc = 0; kc < 2; ++kc)
      #pragma unroll
      for (int m = 0; m < 8; ++m)
        acc[m][nh] = __builtin_amdgcn_mfma_f32_16x16x32_bf16(af[m][kc], bfr[kc],
                                                             acc[m][nh], 0, 0, 0);
  };

#define PH_BEGIN() do { __builtin_amdgcn_s_barrier();                         \
    asm volatile("s_waitcnt lgkmcnt(0)" ::: "memory");                        \
    __builtin_amdgcn_sched_barrier(0);                                        \
    __builtin_amdgcn_s_setprio(1); } while (0)
#define PH_END() do { __builtin_amdgcn_s_setprio(0);                          \
    __builtin_amdgcn_s_barrier(); } while (0)

  STA(0); STB(0); STA(1);
  asm volatile("s_waitcnt vmcnt(4)" ::: "memory");
  __builtin_amdgcn_s_barrier();

  for (int u = 0; u < NT; ++u) {
    LDA(u); LDB(u, 0);
    if (u + 1 < NT) STB(u + 1);
    PH_BEGIN(); MMQ(0); PH_END();
    LDB(u, 1);
    if (u + 2 < NT) STA(u + 2);
    PH_BEGIN(); MMQ(1); PH_END();
    LDB(u, 2);
    PH_BEGIN(); MMQ(2);
    __builtin_amdgcn_s_setprio(0);
    if (u + 2 < NT) { asm volatile("s_waitcnt vmcnt(4)" ::: "memory"); }
    else            { asm volatile("s_waitcnt vmcnt(0)" ::: "memory"); }
    __builtin_amdgcn_s_barrier();
  }
#undef PH_BEGIN
#undef PH_END

  #pragma unroll
  for (int m = 0; m < 8; ++m)
    #pragma unroll
    for (int nh = 0; nh < 3; ++nh)
      #pragma unroll
      for (int j = 0; j < 4; ++j) {
        long r = arow + wr * 128 + m * 16 + l4 * 4 + j;
        long c = brow + wc * 48 + nh * 16 + l15;
        C[r * Ndim + c] = f2bf(acc[m][nh][j]);
      }
}

// ---------------- 256x128 2-phase bf16 GEMM (out-proj; fp32 out) -----
__global__ __launch_bounds__(512, 2) void gemm256(const u16* __restrict__ A,
                                                  const u16* __restrict__ B,
                                                  float* __restrict__ C,
                                                  int Ndim, int Kdim) {
  extern __shared__ __align__(16) u16 lds[];
  const int tid = threadIdx.x;
  const int lane = tid & 63, wave = tid >> 6;
  const int wr = wave >> 2, wc = wave & 3;
  const int l15 = lane & 15, l4 = lane >> 4;
  const int gx = gridDim.x;
  int lin = blockIdx.y * gx + blockIdx.x;
  const int xcd = lin & 7, ii = lin >> 3;
  const int bx = xcd * (gx >> 3) + (ii >> 3), by = ii & 7;
  const long arow = (long)by * 256, brow = (long)bx * 128;
  const int NT = Kdim >> 6;

  const int rowt = tid >> 3;
  const int koff = ((tid & 7) ^ (rowt & 7)) * 8;
  const u16* gA[4];
  const u16* gB[2];
  #pragma unroll
  for (int r = 0; r < 4; ++r) gA[r] = A + (size_t)(arow + rowt + r * 64) * Kdim + koff;
  #pragma unroll
  for (int r = 0; r < 2; ++r) gB[r] = B + (size_t)(brow + rowt + r * 64) * Kdim + koff;

  auto STA = [&](int u) {
    u16* d = lds + (u % 3) * 16384 + tid * 8;
    #pragma unroll
    for (int r = 0; r < 4; ++r) gload16(gA[r] + (size_t)u * 64, d + r * 4096);
  };
  auto STB = [&](int u) {
    u16* d = lds + 49152 + (u & 1) * 8192 + tid * 8;
    #pragma unroll
    for (int r = 0; r < 2; ++r) gload16(gB[r] + (size_t)u * 64, d + r * 4096);
  };

  bf16x8 af[4][2], bfr[2][2];
  f32x4 acc[8][2] = {};
  int cks[2];
  #pragma unroll
  for (int kc = 0; kc < 2; ++kc) cks[kc] = (((kc * 4 + l4) ^ (l15 & 7)) * 8);

  auto LDA = [&](int u, int mh) {
    const u16* base = lds + (u % 3) * 16384 + (wr * 128 + mh * 64 + l15) * 64;
    #pragma unroll
    for (int m = 0; m < 4; ++m)
      #pragma unroll
      for (int kc = 0; kc < 2; ++kc)
        af[m][kc] = *(const bf16x8*)(base + m * 1024 + cks[kc]);
  };
  auto LDB = [&](int u) {
    const u16* base = lds + 49152 + (u & 1) * 8192 + (wc * 32 + l15) * 64;
    #pragma unroll
    for (int n = 0; n < 2; ++n)
      #pragma unroll
      for (int kc = 0; kc < 2; ++kc)
        bfr[n][kc] = *(const bf16x8*)(base + n * 1024 + cks[kc]);
  };
  auto MM = [&](int mh) {
    #pragma unroll
    for (int kc = 0; kc < 2; ++kc)
      #pragma unroll
      for (int m = 0; m < 4; ++m)
        #pragma unroll
        for (int n = 0; n < 2; ++n)
          acc[mh * 4 + m][n] =
            __builtin_amdgcn_mfma_f32_16x16x32_bf16(af[m][kc], bfr[n][kc],
                                                    acc[mh * 4 + m][n], 0, 0, 0);
  };

#define PH_BEGIN() do { __builtin_amdgcn_s_barrier();                         \
    asm volatile("s_waitcnt lgkmcnt(0)" ::: "memory");                        \
    __builtin_amdgcn_sched_barrier(0);                                        \
    __builtin_amdgcn_s_setprio(1); } while (0)

  STA(0); STB(0); STA(1); STB(1);
  asm volatile("s_waitcnt vmcnt(6)" ::: "memory");
  __builtin_amdgcn_s_barrier();

  for (int u = 0; u < NT; ++u) {
    LDA(u, 0); LDB(u);
    if (u + 2 < NT) STA(u + 2);
    PH_BEGIN(); MM(0);
    __builtin_amdgcn_s_setprio(0);
    __builtin_amdgcn_s_barrier();
    LDA(u, 1);
    if (u + 2 < NT) STB(u + 2);
    PH_BEGIN(); MM(1);
    __builtin_amdgcn_s_setprio(0);
    if (u + 2 < NT) { asm volatile("s_waitcnt vmcnt(6)" ::: "memory"); }
    else if (u + 1 < NT) { asm volatile("s_waitcnt vmcnt(0)" ::: "memory"); }
    __builtin_amdgcn_s_barrier();
  }
#undef PH_BEGIN

  #pragma unroll
  for (int M = 0; M < 8; ++M)
    #pragma unroll
    for (int n = 0; n < 2; ++n)
      #pragma unroll
      for (int j = 0; j < 4; ++j) {
        long r = arow + wr * 128 + M * 16 + l4 * 4 + j;
        long c = brow + wc * 32 + n * 16 + l15;
        C[r * Ndim + c] = acc[M][n][j];
      }
}

// ---------------- fused per-head LayerNorm + RoPE, bf16 in/out ----------------
__global__ __launch_bounds__(256) void ln_rope_kernel(
    const u16* __restrict__ qkv, const int* __restrict__ pos,
    const float* __restrict__ qw, const float* __restrict__ qb2,
    const float* __restrict__ kw, const float* __restrict__ kb2,
    u16* __restrict__ qo, u16* __restrict__ ko, u16* __restrict__ vo, int T) {
  const int hh = blockIdx.x;
  const int t = blockIdx.y * 4 + (threadIdx.x >> 6);
  const int lane = threadIdx.x & 63;
  const u16* src = qkv + (size_t)t * 12288 + hh * 128;
  u16 u1 = src[lane], u2 = src[lane + 64];
  if (hh >= 64) {   // v: pure bit-copy to [h][t][d]
    u16* dst = vo + ((size_t)(hh - 64) * T + t) * 128;
    dst[lane] = u1; dst[lane + 64] = u2;
    return;
  }
  float x1 = bf2f(u1), x2 = bf2f(u2);
  float s = x1 + x2;
  #pragma unroll
  for (int off = 32; off; off >>= 1) s += __shfl_xor(s, off);
  float mu = s * (1.0f / 128.0f);
  float d1 = x1 - mu, d2 = x2 - mu;
  float vs = d1 * d1 + d2 * d2;
  #pragma unroll
  for (int off = 32; off; off >>= 1) vs += __shfl_xor(vs, off);
  float rstd = rsqrtf(vs * (1.0f / 128.0f) + 1e-5f);
  bool isq = hh < 32;
  int hl = isq ? hh : hh - 32;
  const float* w = (isq ? qw : kw) + hl * 128;
  const float* b = (isq ? qb2 : kb2) + hl * 128;
  float y1 = d1 * rstd * w[lane] + b[lane];
  float y2 = d2 * rstd * w[lane + 64] + b[lane + 64];
  float p = (float)pos[t];
  float invf = exp2f((float)lane * (-13.287712379549449f / 64.0f));
  float fr = p * invf;
  float sn, cs;
  __sincosf(fr, &sn, &cs);
  float o1 = y1 * cs - y2 * sn;
  float o2 = y2 * cs + y1 * sn;
  if (isq) {
    const float sc = 0.08838834764831845f;   // 1/sqrt(128) folded into q
    o1 *= sc; o2 *= sc;
    u16* dst = qo + ((size_t)hl * T + t) * 128;
    dst[lane] = f2bf(o1); dst[lane + 64] = f2bf(o2);
  } else {
    u16* dst = ko + ((size_t)hl * T + t) * 128;
    dst[lane] = f2bf(o1); dst[lane + 64] = f2bf(o2);
  }
}

// ---------------- flash attention (causal), balanced wave->row map ----------------
// Wave w owns rows qbase + mi*64 + w*16 (mi = 0,1): every wave has one fragment in each
// half of the q-block -> uniform causal depth; fully-masked fragments skipped per-mi.
__global__ __launch_bounds__(256, 2) void flash_kernel(
    const u16* __restrict__ qb, const u16* __restrict__ kb,
    const u16* __restrict__ vb, u16* __restrict__ attn, int T) {
  __shared__ __align__(16) u16 Ks[64 * 128];
  __shared__ __align__(16) u16 Vt[128 * 64];
  __shared__ __align__(16) u16 Ps[4][32 * 64];
  const int tid = threadIdx.x;
  const int lane = tid & 63, wave = tid >> 6;
  const int l15 = lane & 15, l4 = lane >> 4;
  const int h = blockIdx.y;
  const int qbase = blockIdx.x * 128;
  const u16* Q  = qb + (size_t)h * T * 128;
  const u16* Kp = kb + (size_t)h * T * 128;
  const u16* Vp = vb + (size_t)h * T * 128;
  const int rK0 = tid >> 4, d8k = (tid & 15) * 8;

  bf16x8 qf[2][4];
  #pragma unroll
  for (int mi = 0; mi < 2; ++mi)
    #pragma unroll
    for (int kc = 0; kc < 4; ++kc)
      qf[mi][kc] = *(const bf16x8*)&Q[(size_t)(qbase + mi * 64 + wave * 16 + l15) * 128 + kc * 32 + l4 * 8];

  float m_st[2][4], l_st[2][4];
  f32x4 o[2][8] = {};
  #pragma unroll
  for (int mi = 0; mi < 2; ++mi)
    #pragma unroll
    for (int j = 0; j < 4; ++j) { m_st[mi][j] = -1e30f; l_st[mi][j] = 0.0f; }

  const int ntile = (qbase + 128) / 64;
  uint4 kr[4], vr[4];
  #pragma unroll
  for (int c = 0; c < 4; ++c) {
    kr[c] = *(const uint4*)&Kp[(size_t)(rK0 + 16 * c) * 128 + d8k];
    vr[c] = *(const uint4*)&Vp[(size_t)lane * 128 + (wave + 4 * c) * 8];
  }
  for (int kt = 0; kt < ntile; ++kt) {
    const int kbase = kt * 64;
    #pragma unroll
    for (int c = 0; c < 4; ++c) {
      *(uint4*)&Ks[swz128i(rK0 + 16 * c, d8k)] = kr[c];
      const u16* pv = (const u16*)&vr[c];
      int dv = (wave + 4 * c) * 8;
      #pragma unroll
      for (int j = 0; j < 8; ++j) Vt[swz64i(dv + j, lane)] = pv[j];
    }
    __syncthreads();
    if (kt + 1 < ntile) {
      const int nb = kbase + 64;
      #pragma unroll
      for (int c = 0; c < 4; ++c) {
        kr[c] = *(const uint4*)&Kp[(size_t)(nb + rK0 + 16 * c) * 128 + d8k];
        vr[c] = *(const uint4*)&Vp[(size_t)(nb + lane) * 128 + (wave + 4 * c) * 8];
      }
    }
    #pragma unroll
    for (int mi = 0; mi < 2; ++mi) {
      const int r0 = qbase + mi * 64 + wave * 16;   // fragment row base (wave-uniform)
      if (kbase <= r0 + 15) {
        f32x4 s[4] = {};
        __builtin_amdgcn_s_setprio(1);
        #pragma unroll
        for (int kc = 0; kc < 4; ++kc)
          #pragma unroll
          for (int nj = 0; nj < 4; ++nj) {
            bf16x8 kf = *(const bf16x8*)&Ks[swz128i(nj * 16 + l15, kc * 32 + l4 * 8)];
            s[nj] = __builtin_amdgcn_mfma_f32_16x16x32_bf16(qf[mi][kc], kf, s[nj], 0, 0, 0);
          }
        __builtin_amdgcn_s_setprio(0);
        if (kbase + 63 > r0) {   // diagonal for this fragment
          #pragma unroll
          for (int nj = 0; nj < 4; ++nj)
            #pragma unroll
            for (int j = 0; j < 4; ++j) {
              int r = r0 + l4 * 4 + j;
              int cc = kbase + nj * 16 + l15;
              if (cc > r) s[nj][j] = -1e30f;
            }
        }
        float vmax[4];
        float dmax = -1e30f;
        #pragma unroll
        for (int j = 0; j < 4; ++j) {
          float v = fmaxf(fmaxf(s[0][j], s[1][j]), fmaxf(s[2][j], s[3][j]));
          #pragma unroll
          for (int off = 1; off < 16; off <<= 1) v = fmaxf(v, __shfl_xor(v, off));
          vmax[j] = v;
          dmax = fmaxf(dmax, v - m_st[mi][j]);
        }
        if (!__all(dmax <= 8.0f)) {
          #pragma unroll
          for (int j = 0; j < 4; ++j) {
            float mn = fmaxf(m_st[mi][j], vmax[j]);
            float scl = __expf(m_st[mi][j] - mn);
            m_st[mi][j] = mn;
            l_st[mi][j] *= scl;
            #pragma unroll
            for (int nf = 0; nf < 8; ++nf) o[mi][nf][j] *= scl;
          }
        }
        float sum[4] = {0.f, 0.f, 0.f, 0.f};
        #pragma unroll
        for (int nj = 0; nj < 4; ++nj)
          #pragma unroll
          for (int j = 0; j < 4; ++j) {
            float p = __expf(s[nj][j] - m_st[mi][j]);
            s[nj][j] = p;
            sum[j] += p;
          }
        #pragma unroll
        for (int j = 0; j < 4; ++j) {
          #pragma unroll
          for (int off = 1; off < 16; off <<= 1) sum[j] += __shfl_xor(sum[j], off);
          l_st[mi][j] += sum[j];
        }
        #pragma unroll
        for (int nj = 0; nj < 4; ++nj)
          #pragma unroll
          for (int j = 0; j < 4; ++j)
            Ps[wave][swz64i(mi * 16 + l4 * 4 + j, nj * 16 + l15)] = f2bf(s[nj][j]);
        asm volatile("s_waitcnt lgkmcnt(0)" ::: "memory");
        __builtin_amdgcn_sched_barrier(0);
        __builtin_amdgcn_s_setprio(1);
        #pragma unroll
        for (int kc = 0; kc < 2; ++kc) {
          bf16x8 pf = *(const bf16x8*)&Ps[wave][swz64i(mi * 16 + l15, kc * 32 + l4 * 8)];
          #pragma unroll
          for (int nf = 0; nf < 8; ++nf) {
            bf16x8 vf = *(const bf16x8*)&Vt[swz64i(nf * 16 + l15, kc * 32 + l4 * 8)];
            o[mi][nf] = __builtin_amdgcn_mfma_f32_16x16x32_bf16(pf, vf, o[mi][nf], 0, 0, 0);
          }
        }
        __builtin_amdgcn_s_setprio(0);
      }
    }
    __syncthreads();
  }
  #pragma unroll
  for (int mi = 0; mi < 2; ++mi) {
    float rl[4];
    #pragma unroll
    for (int j = 0; j < 4; ++j) rl[j] = 1.0f / l_st[mi][j];
    #pragma unroll
    for (int nf = 0; nf < 8; ++nf)
      #pragma unroll
      for (int j = 0; j < 4; ++j) {
        int r = qbase + mi * 64 + wave * 16 + l4 * 4 + j;
        int cc = h * 128 + nf * 16 + l15;
        attn[(size_t)r * 4096 + cc] = f2bf(o[mi][nf][j] * rl[j]);
      }
  }
}

// ---------------- launch ----------------
extern "C" void kernel_launch(void* const* d_in, const int* in_sizes, int n_in,
                              void* d_out, int out_size, void* d_ws, size_t ws_size,
                              hipStream_t stream) {
  const int* positions = (const int*)d_in[0];
  const float* hidden  = (const float*)d_in[1];
  const float* w_qkv   = (const float*)d_in[2];
  const float* w_o     = (const float*)d_in[3];
  const float* qnw     = (const float*)d_in[4];
  const float* qnb     = (const float*)d_in[5];
  const float* knw     = (const float*)d_in[6];
  const float* knb     = (const float*)d_in[7];
  float* out = (float*)d_out;

  const int T = in_sizes[0];           // 2048
  const int HID = 4096, NQKV = 12288, H = 32;

  char* ws = (char*)d_ws;
  u16* hid_bf  = (u16*)ws;
  u16* wreg    = (u16*)(ws + (size_t)T * HID * 2);
  u16* qkv_bf  = (u16*)(ws + (size_t)T * HID * 2 + (size_t)NQKV * HID * 2);  // [T][12288] bf16

  u16* q_bf  = wreg;                                 // [H][T][128]
  u16* k_bf  = q_bf + (size_t)H * T * 128;           // [H][T][128]
  u16* v_bf  = k_bf + (size_t)H * T * 128;           // [H][T][128]
  u16* at_bf = v_bf + (size_t)H * T * 128;           // [T][H*128]
  u16* wo_bf = at_bf + (size_t)T * 4096;             // [4096][4096]

  hipFuncSetAttribute(reinterpret_cast<const void*>(&gemm192),
                      hipFuncAttributeMaxDynamicSharedMemorySize, 114688);
  hipFuncSetAttribute(reinterpret_cast<const void*>(&gemm256),
                      hipFuncAttributeMaxDynamicSharedMemorySize, 131072);

  cvt_bf16_kernel<<<2048, 256, 0, stream>>>(hidden, hid_bf, (long)T * HID / 4);
  cvt_bf16_kernel<<<4096, 256, 0, stream>>>(w_qkv, wreg, (long)NQKV * HID / 4);
  gemm192<<<dim3(NQKV / 192, T / 256), 512, 114688, stream>>>(hid_bf, wreg, qkv_bf, NQKV, HID);
  ln_rope_kernel<<<dim3(96, T / 4), 256, 0, stream>>>(qkv_bf, positions, qnw, qnb, knw, knb,
                                                      q_bf, k_bf, v_bf, T);
  cvt_bf16_kernel<<<2048, 256, 0, stream>>>(w_o, wo_bf, (long)HID * HID / 4);
  flash_kernel<<<dim3(T / 128, H), 256, 0, stream>>>(q_bf, k_bf, v_bf, at_bf, T);
  gemm256<<<dim3(HID / 128, T / 256), 512, 131072, stream>>>(at_bf, wo_bf, out, HID, HID);
}

// Round 10
// 498.625 us; speedup vs baseline: 1.1409x; 1.0909x over previous
//
#include <hip/hip_runtime.h>
#include <cstdint>

typedef unsigned short u16;
typedef __attribute__((ext_vector_type(8))) __bf16 bf16x8;
typedef __attribute__((ext_vector_type(4))) float f32x4;

__device__ __forceinline__ u16 f2bf(float f) {
  unsigned int u = __builtin_bit_cast(unsigned int, f);
  unsigned int r = (u + 0x7fffu + ((u >> 16) & 1u)) >> 16;
  return (u16)r;
}
__device__ __forceinline__ float bf2f(u16 u) {
  return __builtin_bit_cast(float, (unsigned int)u << 16);
}

// async global->LDS, 16B per lane. LDS dest must be linear in lane (wave base + lane*16).
__device__ __forceinline__ void gload16(const u16* g, u16* l) {
  __builtin_amdgcn_global_load_lds((const __attribute__((address_space(1))) void*)g,
                                   (__attribute__((address_space(3))) void*)l, 16, 0, 0);
}

// XOR-swizzle helpers for flash kernel LDS.
__device__ __forceinline__ int swz64i(int row, int col) {   // 64 u16 cols per row
  return row * 64 + (((col & 0x38) ^ ((row & 7) << 3)) | (col & 7));
}
__device__ __forceinline__ int swz128i(int row, int col) {  // 128 u16 cols per row
  return row * 128 + (((col & 0x78) ^ ((row & 7) << 3)) | (col & 7));
}

// ---------------- fp32 -> bf16 conversion ----------------
__global__ __launch_bounds__(256) void cvt_bf16_kernel(const float* __restrict__ in,
                                                       u16* __restrict__ out, long n4) {
  long i = (long)blockIdx.x * 256 + threadIdx.x;
  long stride = (long)gridDim.x * 256;
  const float4* in4 = (const float4*)in;
  uint2* out2 = (uint2*)out;
  for (long k = i; k < n4; k += stride) {
    float4 v = in4[k];
    uint2 o;
    o.x = (unsigned int)f2bf(v.x) | ((unsigned int)f2bf(v.y) << 16);
    o.y = (unsigned int)f2bf(v.z) | ((unsigned int)f2bf(v.w) << 16);
    out2[k] = o;
  }
}

// ---------------- 256x192 2-phase m-split bf16 GEMM (QKV; bf16 out) ----
// C[M][N] = A[M][K]*B[N][K]^T. BK=64, 512 thr, 8 waves 2Mx4N, wave 128x48.
// Phases: ph1 {af[m0-3] 8r + bfr all 6r | STB(u+1)} 24 MFMA; ph2 {af[m4-7] 8r | STA(u+2)} 24 MFMA.
// A TRIPLE-buffered (u%3) so ph2's STA(u+2) never hits the buffer being read. B dbuf.
// vmcnt: ph2-end = vmcnt(4) steady (drains A(u+1)+B(u), keeps STA(u+2)); tails vmcnt(0).
// LDS 144KB. Requires gridDim.x % 8 == 0, K % 64 == 0, K/64 >= 3.
__global__ __launch_bounds__(512, 2) void gemm192(const u16* __restrict__ A,
                                                  const u16* __restrict__ B,
                                                  u16* __restrict__ C,
                                                  int Ndim, int Kdim) {
  extern __shared__ __align__(16) u16 lds[];   // A: 3*16384 u16 @0, B: 2*12288 u16 @49152
  const int tid = threadIdx.x;
  const int lane = tid & 63, wave = tid >> 6;
  const int wr = wave >> 2, wc = wave & 3;
  const int l15 = lane & 15, l4 = lane >> 4;
  const int gx = gridDim.x;
  int lin = blockIdx.y * gx + blockIdx.x;
  const int xcd = lin & 7, ii = lin >> 3;
  const int bx = xcd * (gx >> 3) + (ii >> 3), by = ii & 7;
  const long arow = (long)by * 256, brow = (long)bx * 192;
  const int NT = Kdim >> 6;

  const int rowt = tid >> 3;
  const int koff = ((tid & 7) ^ (rowt & 7)) * 8;
  const u16* gA[4];
  const u16* gB[3];
  #pragma unroll
  for (int r = 0; r < 4; ++r) gA[r] = A + (size_t)(arow + rowt + r * 64) * Kdim + koff;
  #pragma unroll
  for (int r = 0; r < 3; ++r) gB[r] = B + (size_t)(brow + rowt + r * 64) * Kdim + koff;
  u16* const ldsB = lds + 49152;

  auto STA = [&](int u) {   // 4 gloads -> A-buf u%3
    u16* d = lds + (u % 3) * 16384 + tid * 8;
    #pragma unroll
    for (int r = 0; r < 4; ++r) gload16(gA[r] + (size_t)u * 64, d + r * 4096);
  };
  auto STB = [&](int u) {   // 3 gloads -> B-buf u&1
    u16* d = ldsB + (u & 1) * 12288 + tid * 8;
    #pragma unroll
    for (int r = 0; r < 3; ++r) gload16(gB[r] + (size_t)u * 64, d + r * 4096);
  };

  bf16x8 af[4][2], bfr[3][2];
  f32x4 acc[8][3] = {};
  int cks[2];
  #pragma unroll
  for (int kc = 0; kc < 2; ++kc) cks[kc] = (((kc * 4 + l4) ^ (l15 & 7)) * 8);

  auto LDA4 = [&](int u, int mh) {  // 8 x ds_read_b128: af half mh
    const u16* base = lds + (u % 3) * 16384 + (wr * 128 + mh * 64 + l15) * 64;
    #pragma unroll
    for (int m = 0; m < 4; ++m)
      #pragma unroll
      for (int kc = 0; kc < 2; ++kc)
        af[m][kc] = *(const bf16x8*)(base + m * 1024 + cks[kc]);
  };
  auto LDBall = [&](int u) {        // 6 x ds_read_b128: all 3 n-frags
    const u16* base = ldsB + (u & 1) * 12288 + (wc * 48 + l15) * 64;
    #pragma unroll
    for (int nh = 0; nh < 3; ++nh)
      #pragma unroll
      for (int kc = 0; kc < 2; ++kc)
        bfr[nh][kc] = *(const bf16x8*)(base + nh * 1024 + cks[kc]);
  };
  auto MM24 = [&](int mh) {         // 24 MFMA, kc outermost (acc reuse 12 apart)
    #pragma unroll
    for (int kc = 0; kc < 2; ++kc)
      #pragma unroll
      for (int m = 0; m < 4; ++m)
        #pragma unroll
        for (int nh = 0; nh < 3; ++nh)
          acc[mh * 4 + m][nh] = __builtin_amdgcn_mfma_f32_16x16x32_bf16(
              af[m][kc], bfr[nh][kc], acc[mh * 4 + m][nh], 0, 0, 0);
  };

#define PH_BEGIN() do { __builtin_amdgcn_s_barrier();                         \
    asm volatile("s_waitcnt lgkmcnt(0)" ::: "memory");                        \
    __builtin_amdgcn_sched_barrier(0);                                        \
    __builtin_amdgcn_s_setprio(1); } while (0)
#define PH_END() do { __builtin_amdgcn_s_setprio(0);                          \
    __builtin_amdgcn_s_barrier(); } while (0)

  // prologue: outstanding STA(0)4+STB(0)3+STA(1)4=11 -> vmcnt(4) drains A0,B0, keeps STA(1).
  STA(0); STB(0); STA(1);
  asm volatile("s_waitcnt vmcnt(4)" ::: "memory");
  __builtin_amdgcn_s_barrier();

  for (int u = 0; u < NT; ++u) {
    // ph1: A half 0 + all B ; stage B(u+1)
    LDA4(u, 0); LDBall(u);
    if (u + 1 < NT) STB(u + 1);
    PH_BEGIN(); MM24(0); PH_END();
    // ph2: A half 1 ; stage A(u+2) (different A buffer: (u+2)%3 != u%3)
    LDA4(u, 1);
    if (u + 2 < NT) STA(u + 2);
    PH_BEGIN(); MM24(1);
    __builtin_amdgcn_s_setprio(0);
    if (u + 2 < NT) { asm volatile("s_waitcnt vmcnt(4)" ::: "memory"); }
    else            { asm volatile("s_waitcnt vmcnt(0)" ::: "memory"); }
    __builtin_amdgcn_s_barrier();
  }
#undef PH_BEGIN
#undef PH_END

  #pragma unroll
  for (int m = 0; m < 8; ++m)
    #pragma unroll
    for (int nh = 0; nh < 3; ++nh)
      #pragma unroll
      for (int j = 0; j < 4; ++j) {
        long r = arow + wr * 128 + m * 16 + l4 * 4 + j;
        long c = brow + wc * 48 + nh * 16 + l15;
        C[r * Ndim + c] = f2bf(acc[m][nh][j]);
      }
}

// ---------------- 256x128 2-phase bf16 GEMM (out-proj; fp32 out) -----
__global__ __launch_bounds__(512, 2) void gemm256(const u16* __restrict__ A,
                                                  const u16* __restrict__ B,
                                                  float* __restrict__ C,
                                                  int Ndim, int Kdim) {
  extern __shared__ __align__(16) u16 lds[];
  const int tid = threadIdx.x;
  const int lane = tid & 63, wave = tid >> 6;
  const int wr = wave >> 2, wc = wave & 3;
  const int l15 = lane & 15, l4 = lane >> 4;
  const int gx = gridDim.x;
  int lin = blockIdx.y * gx + blockIdx.x;
  const int xcd = lin & 7, ii = lin >> 3;
  const int bx = xcd * (gx >> 3) + (ii >> 3), by = ii & 7;
  const long arow = (long)by * 256, brow = (long)bx * 128;
  const int NT = Kdim >> 6;

  const int rowt = tid >> 3;
  const int koff = ((tid & 7) ^ (rowt & 7)) * 8;
  const u16* gA[4];
  const u16* gB[2];
  #pragma unroll
  for (int r = 0; r < 4; ++r) gA[r] = A + (size_t)(arow + rowt + r * 64) * Kdim + koff;
  #pragma unroll
  for (int r = 0; r < 2; ++r) gB[r] = B + (size_t)(brow + rowt + r * 64) * Kdim + koff;

  auto STA = [&](int u) {
    u16* d = lds + (u % 3) * 16384 + tid * 8;
    #pragma unroll
    for (int r = 0; r < 4; ++r) gload16(gA[r] + (size_t)u * 64, d + r * 4096);
  };
  auto STB = [&](int u) {
    u16* d = lds + 49152 + (u & 1) * 8192 + tid * 8;
    #pragma unroll
    for (int r = 0; r < 2; ++r) gload16(gB[r] + (size_t)u * 64, d + r * 4096);
  };

  bf16x8 af[4][2], bfr[2][2];
  f32x4 acc[8][2] = {};
  int cks[2];
  #pragma unroll
  for (int kc = 0; kc < 2; ++kc) cks[kc] = (((kc * 4 + l4) ^ (l15 & 7)) * 8);

  auto LDA = [&](int u, int mh) {
    const u16* base = lds + (u % 3) * 16384 + (wr * 128 + mh * 64 + l15) * 64;
    #pragma unroll
    for (int m = 0; m < 4; ++m)
      #pragma unroll
      for (int kc = 0; kc < 2; ++kc)
        af[m][kc] = *(const bf16x8*)(base + m * 1024 + cks[kc]);
  };
  auto LDB = [&](int u) {
    const u16* base = lds + 49152 + (u & 1) * 8192 + (wc * 32 + l15) * 64;
    #pragma unroll
    for (int n = 0; n < 2; ++n)
      #pragma unroll
      for (int kc = 0; kc < 2; ++kc)
        bfr[n][kc] = *(const bf16x8*)(base + n * 1024 + cks[kc]);
  };
  auto MM = [&](int mh) {
    #pragma unroll
    for (int kc = 0; kc < 2; ++kc)
      #pragma unroll
      for (int m = 0; m < 4; ++m)
        #pragma unroll
        for (int n = 0; n < 2; ++n)
          acc[mh * 4 + m][n] =
            __builtin_amdgcn_mfma_f32_16x16x32_bf16(af[m][kc], bfr[n][kc],
                                                    acc[mh * 4 + m][n], 0, 0, 0);
  };

#define PH_BEGIN() do { __builtin_amdgcn_s_barrier();                         \
    asm volatile("s_waitcnt lgkmcnt(0)" ::: "memory");                        \
    __builtin_amdgcn_sched_barrier(0);                                        \
    __builtin_amdgcn_s_setprio(1); } while (0)

  STA(0); STB(0); STA(1); STB(1);
  asm volatile("s_waitcnt vmcnt(6)" ::: "memory");
  __builtin_amdgcn_s_barrier();

  for (int u = 0; u < NT; ++u) {
    LDA(u, 0); LDB(u);
    if (u + 2 < NT) STA(u + 2);
    PH_BEGIN(); MM(0);
    __builtin_amdgcn_s_setprio(0);
    __builtin_amdgcn_s_barrier();
    LDA(u, 1);
    if (u + 2 < NT) STB(u + 2);
    PH_BEGIN(); MM(1);
    __builtin_amdgcn_s_setprio(0);
    if (u + 2 < NT) { asm volatile("s_waitcnt vmcnt(6)" ::: "memory"); }
    else if (u + 1 < NT) { asm volatile("s_waitcnt vmcnt(0)" ::: "memory"); }
    __builtin_amdgcn_s_barrier();
  }
#undef PH_BEGIN

  #pragma unroll
  for (int M = 0; M < 8; ++M)
    #pragma unroll
    for (int n = 0; n < 2; ++n)
      #pragma unroll
      for (int j = 0; j < 4; ++j) {
        long r = arow + wr * 128 + M * 16 + l4 * 4 + j;
        long c = brow + wc * 32 + n * 16 + l15;
        C[r * Ndim + c] = acc[M][n][j];
      }
}

// ---------------- fused per-head LayerNorm + RoPE, bf16 in/out ----------------
__global__ __launch_bounds__(256) void ln_rope_kernel(
    const u16* __restrict__ qkv, const int* __restrict__ pos,
    const float* __restrict__ qw, const float* __restrict__ qb2,
    const float* __restrict__ kw, const float* __restrict__ kb2,
    u16* __restrict__ qo, u16* __restrict__ ko, u16* __restrict__ vo, int T) {
  const int hh = blockIdx.x;
  const int t = blockIdx.y * 4 + (threadIdx.x >> 6);
  const int lane = threadIdx.x & 63;
  const u16* src = qkv + (size_t)t * 12288 + hh * 128;
  u16 u1 = src[lane], u2 = src[lane + 64];
  if (hh >= 64) {
    u16* dst = vo + ((size_t)(hh - 64) * T + t) * 128;
    dst[lane] = u1; dst[lane + 64] = u2;
    return;
  }
  float x1 = bf2f(u1), x2 = bf2f(u2);
  float s = x1 + x2;
  #pragma unroll
  for (int off = 32; off; off >>= 1) s += __shfl_xor(s, off);
  float mu = s * (1.0f / 128.0f);
  float d1 = x1 - mu, d2 = x2 - mu;
  float vs = d1 * d1 + d2 * d2;
  #pragma unroll
  for (int off = 32; off; off >>= 1) vs += __shfl_xor(vs, off);
  float rstd = rsqrtf(vs * (1.0f / 128.0f) + 1e-5f);
  bool isq = hh < 32;
  int hl = isq ? hh : hh - 32;
  const float* w = (isq ? qw : kw) + hl * 128;
  const float* b = (isq ? qb2 : kb2) + hl * 128;
  float y1 = d1 * rstd * w[lane] + b[lane];
  float y2 = d2 * rstd * w[lane + 64] + b[lane + 64];
  float p = (float)pos[t];
  float invf = exp2f((float)lane * (-13.287712379549449f / 64.0f));
  float fr = p * invf;
  float sn, cs;
  __sincosf(fr, &sn, &cs);
  float o1 = y1 * cs - y2 * sn;
  float o2 = y2 * cs + y1 * sn;
  if (isq) {
    const float sc = 0.08838834764831845f;   // 1/sqrt(128) folded into q
    o1 *= sc; o2 *= sc;
    u16* dst = qo + ((size_t)hl * T + t) * 128;
    dst[lane] = f2bf(o1); dst[lane + 64] = f2bf(o2);
  } else {
    u16* dst = ko + ((size_t)hl * T + t) * 128;
    dst[lane] = f2bf(o1); dst[lane + 64] = f2bf(o2);
  }
}

// ---------------- flash attention (causal), PAIRED q-tiles for load balance ----------
// Block bxp pairs q-tiles (nqt-1-bxp) [long, waves 0-3] and bxp [short, waves 4-7].
// 512 thr / 8 waves; each wave 32 rows (2 mi frags at r0 = qbase+mi*64+(w&3)*16).
// Per-SIMD load = one long + one short wave = uniform across the whole GPU.
// Grid: (nqt/2, H) = 256 blocks, 1/CU. Dynamic LDS 64KB: Ks|Vt|Ps[8].
__global__ __launch_bounds__(512, 2) void flash_kernel(
    const u16* __restrict__ qb, const u16* __restrict__ kb,
    const u16* __restrict__ vb, u16* __restrict__ attn, int T) {
  extern __shared__ __align__(16) u16 flds[];
  u16* const Ks = flds;            // 64x128 swizzled (8192 u16)
  u16* const Vt = flds + 8192;     // 128x64 transposed swizzled (8192 u16)
  u16* const Ps = flds + 16384;    // 8 x (32x64) per-wave
  const int tid = threadIdx.x;
  const int lane = tid & 63, wave = tid >> 6;
  const int wl = wave & 3;
  const int l15 = lane & 15, l4 = lane >> 4;
  const int h = blockIdx.y;
  const int nqt = T >> 7;
  const int qt = (wave < 4) ? (nqt - 1 - blockIdx.x) : blockIdx.x;
  const int qbase = qt * 128;
  const u16* Q  = qb + (size_t)h * T * 128;
  const u16* Kp = kb + (size_t)h * T * 128;
  const u16* Vp = vb + (size_t)h * T * 128;
  // staging map (512 thr): K rows tid>>4 (+32), 16B piece (tid&15)*8;
  // V row tid&63, d-chunks (tid>>6)*8 and +64.
  const int rK = tid >> 4, d8k = (tid & 15) * 8;
  const int rv = tid & 63, dv0 = (tid >> 6) * 8;
  u16* const Pw = Ps + wave * 2048;

  bf16x8 qf[2][4];
  #pragma unroll
  for (int mi = 0; mi < 2; ++mi)
    #pragma unroll
    for (int kc = 0; kc < 4; ++kc)
      qf[mi][kc] = *(const bf16x8*)&Q[(size_t)(qbase + mi * 64 + wl * 16 + l15) * 128 + kc * 32 + l4 * 8];

  float m_st[2][4], l_st[2][4];
  f32x4 o[2][8] = {};
  #pragma unroll
  for (int mi = 0; mi < 2; ++mi)
    #pragma unroll
    for (int j = 0; j < 4; ++j) { m_st[mi][j] = -1e30f; l_st[mi][j] = 0.0f; }

  const int ntile = 2 * (nqt - 1 - blockIdx.x) + 2;   // long tile's range
  uint4 kr[2], vr[2];
  #pragma unroll
  for (int c = 0; c < 2; ++c) {
    kr[c] = *(const uint4*)&Kp[(size_t)(rK + 32 * c) * 128 + d8k];
    vr[c] = *(const uint4*)&Vp[(size_t)rv * 128 + dv0 + 64 * c];
  }
  for (int kt = 0; kt < ntile; ++kt) {
    const int kbase = kt * 64;
    #pragma unroll
    for (int c = 0; c < 2; ++c) {
      *(uint4*)&Ks[swz128i(rK + 32 * c, d8k)] = kr[c];
      const u16* pv = (const u16*)&vr[c];
      #pragma unroll
      for (int j = 0; j < 8; ++j) Vt[swz64i(dv0 + 64 * c + j, rv)] = pv[j];
    }
    __syncthreads();
    if (kt + 1 < ntile) {
      const int nb = kbase + 64;
      #pragma unroll
      for (int c = 0; c < 2; ++c) {
        kr[c] = *(const uint4*)&Kp[(size_t)(nb + rK + 32 * c) * 128 + d8k];
        vr[c] = *(const uint4*)&Vp[(size_t)(nb + rv) * 128 + dv0 + 64 * c];
      }
    }
    #pragma unroll
    for (int mi = 0; mi < 2; ++mi) {
      const int r0 = qbase + mi * 64 + wl * 16;   // wave-uniform fragment base
      if (kbase <= r0 + 15) {
        f32x4 s[4] = {};
        __builtin_amdgcn_s_setprio(1);
        #pragma unroll
        for (int kc = 0; kc < 4; ++kc)
          #pragma unroll
          for (int nj = 0; nj < 4; ++nj) {
            bf16x8 kf = *(const bf16x8*)&Ks[swz128i(nj * 16 + l15, kc * 32 + l4 * 8)];
            s[nj] = __builtin_amdgcn_mfma_f32_16x16x32_bf16(qf[mi][kc], kf, s[nj], 0, 0, 0);
          }
        __builtin_amdgcn_s_setprio(0);
        if (kbase + 63 > r0) {
          #pragma unroll
          for (int nj = 0; nj < 4; ++nj)
            #pragma unroll
            for (int j = 0; j < 4; ++j) {
              int r = r0 + l4 * 4 + j;
              int cc = kbase + nj * 16 + l15;
              if (cc > r) s[nj][j] = -1e30f;
            }
        }
        float vmax[4];
        float dmax = -1e30f;
        #pragma unroll
        for (int j = 0; j < 4; ++j) {
          float v = fmaxf(fmaxf(s[0][j], s[1][j]), fmaxf(s[2][j], s[3][j]));
          #pragma unroll
          for (int off = 1; off < 16; off <<= 1) v = fmaxf(v, __shfl_xor(v, off));
          vmax[j] = v;
          dmax = fmaxf(dmax, v - m_st[mi][j]);
        }
        if (!__all(dmax <= 8.0f)) {
          #pragma unroll
          for (int j = 0; j < 4; ++j) {
            float mn = fmaxf(m_st[mi][j], vmax[j]);
            float scl = __expf(m_st[mi][j] - mn);
            m_st[mi][j] = mn;
            l_st[mi][j] *= scl;
            #pragma unroll
            for (int nf = 0; nf < 8; ++nf) o[mi][nf][j] *= scl;
          }
        }
        float sum[4] = {0.f, 0.f, 0.f, 0.f};
        #pragma unroll
        for (int nj = 0; nj < 4; ++nj)
          #pragma unroll
          for (int j = 0; j < 4; ++j) {
            float p = __expf(s[nj][j] - m_st[mi][j]);
            s[nj][j] = p;
            sum[j] += p;
          }
        #pragma unroll
        for (int j = 0; j < 4; ++j) {
          #pragma unroll
          for (int off = 1; off < 16; off <<= 1) sum[j] += __shfl_xor(sum[j], off);
          l_st[mi][j] += sum[j];
        }
        #pragma unroll
        for (int nj = 0; nj < 4; ++nj)
          #pragma unroll
          for (int j = 0; j < 4; ++j)
            Pw[swz64i(mi * 16 + l4 * 4 + j, nj * 16 + l15)] = f2bf(s[nj][j]);
        asm volatile("s_waitcnt lgkmcnt(0)" ::: "memory");
        __builtin_amdgcn_sched_barrier(0);
        __builtin_amdgcn_s_setprio(1);
        #pragma unroll
        for (int kc = 0; kc < 2; ++kc) {
          bf16x8 pf = *(const bf16x8*)&Pw[swz64i(mi * 16 + l15, kc * 32 + l4 * 8)];
          #pragma unroll
          for (int nf = 0; nf < 8; ++nf) {
            bf16x8 vf = *(const bf16x8*)&Vt[swz64i(nf * 16 + l15, kc * 32 + l4 * 8)];
            o[mi][nf] = __builtin_amdgcn_mfma_f32_16x16x32_bf16(pf, vf, o[mi][nf], 0, 0, 0);
          }
        }
        __builtin_amdgcn_s_setprio(0);
      }
    }
    __syncthreads();
  }
  #pragma unroll
  for (int mi = 0; mi < 2; ++mi) {
    float rl[4];
    #pragma unroll
    for (int j = 0; j < 4; ++j) rl[j] = 1.0f / l_st[mi][j];
    #pragma unroll
    for (int nf = 0; nf < 8; ++nf)
      #pragma unroll
      for (int j = 0; j < 4; ++j) {
        int r = qbase + mi * 64 + wl * 16 + l4 * 4 + j;
        int cc = h * 128 + nf * 16 + l15;
        attn[(size_t)r * 4096 + cc] = f2bf(o[mi][nf][j] * rl[j]);
      }
  }
}

// ---------------- launch ----------------
extern "C" void kernel_launch(void* const* d_in, const int* in_sizes, int n_in,
                              void* d_out, int out_size, void* d_ws, size_t ws_size,
                              hipStream_t stream) {
  const int* positions = (const int*)d_in[0];
  const float* hidden  = (const float*)d_in[1];
  const float* w_qkv   = (const float*)d_in[2];
  const float* w_o     = (const float*)d_in[3];
  const float* qnw     = (const float*)d_in[4];
  const float* qnb     = (const float*)d_in[5];
  const float* knw     = (const float*)d_in[6];
  const float* knb     = (const float*)d_in[7];
  float* out = (float*)d_out;

  const int T = in_sizes[0];           // 2048
  const int HID = 4096, NQKV = 12288, H = 32;

  char* ws = (char*)d_ws;
  u16* hid_bf  = (u16*)ws;
  u16* wreg    = (u16*)(ws + (size_t)T * HID * 2);
  u16* qkv_bf  = (u16*)(ws + (size_t)T * HID * 2 + (size_t)NQKV * HID * 2);

  u16* q_bf  = wreg;                                 // [H][T][128]
  u16* k_bf  = q_bf + (size_t)H * T * 128;
  u16* v_bf  = k_bf + (size_t)H * T * 128;
  u16* at_bf = v_bf + (size_t)H * T * 128;           // [T][H*128]
  u16* wo_bf = at_bf + (size_t)T * 4096;             // [4096][4096]

  hipFuncSetAttribute(reinterpret_cast<const void*>(&gemm192),
                      hipFuncAttributeMaxDynamicSharedMemorySize, 147456);
  hipFuncSetAttribute(reinterpret_cast<const void*>(&gemm256),
                      hipFuncAttributeMaxDynamicSharedMemorySize, 131072);
  hipFuncSetAttribute(reinterpret_cast<const void*>(&flash_kernel),
                      hipFuncAttributeMaxDynamicSharedMemorySize, 65536);

  cvt_bf16_kernel<<<2048, 256, 0, stream>>>(hidden, hid_bf, (long)T * HID / 4);
  cvt_bf16_kernel<<<4096, 256, 0, stream>>>(w_qkv, wreg, (long)NQKV * HID / 4);
  gemm192<<<dim3(NQKV / 192, T / 256), 512, 147456, stream>>>(hid_bf, wreg, qkv_bf, NQKV, HID);
  ln_rope_kernel<<<dim3(96, T / 4), 256, 0, stream>>>(qkv_bf, positions, qnw, qnb, knw, knb,
                                                      q_bf, k_bf, v_bf, T);
  cvt_bf16_kernel<<<2048, 256, 0, stream>>>(w_o, wo_bf, (long)HID * HID / 4);
  flash_kernel<<<dim3(T / 256, H), 512, 65536, stream>>>(q_bf, k_bf, v_bf, at_bf, T);
  gemm256<<<dim3(HID / 128, T / 256), 512, 131072, stream>>>(at_bf, wo_bf, out, HID, HID);
}